// Round 6
// baseline (453.880 us; speedup 1.0000x reference)
//
#include <hip/hip_runtime.h>
#include <math.h>

typedef short s16x8 __attribute__((ext_vector_type(8)));
typedef float f32x4 __attribute__((ext_vector_type(4)));

__device__ inline ushort f2bf(float f) {
  unsigned u = __float_as_uint(f);
  u = (u + 0x7FFF + ((u >> 16) & 1)) >> 16;
  return (ushort)u;
}
__device__ inline float bf2f(ushort u) {
  return __uint_as_float(((unsigned)u) << 16);
}
__device__ inline void gload_lds16(const void* g, void* l) {
  __builtin_amdgcn_global_load_lds(
      (const __attribute__((address_space(1))) unsigned*)g,
      (__attribute__((address_space(3))) unsigned*)l, 16, 0, 0);
}

// ---- K0: Wb bf16[640][kk*64+ci] (kk-major K-perm) + Bc[640] + Wb2 bf16[64][k*64+c] ----
__global__ __launch_bounds__(256) void k_merge(
    const float* __restrict__ wp, const float* __restrict__ bp,
    const float* __restrict__ wm, const float* __restrict__ bm,
    const float* __restrict__ wc, const float* __restrict__ bc,
    const float* __restrict__ wconv,
    ushort* __restrict__ Wb, float* __restrict__ Bc, ushort* __restrict__ Wb2) {
  int i = blockIdx.x * 256 + threadIdx.x;
  if (i < 640 * 576) {
    int g = i / 576, r = i - g * 576;
    int kk = r >> 6, ci = r & 63;
    int col = ci * 9 + kk;               // original OIHW k-index
    float v = 0.f;
    if (g < 18)       v = wp[g * 576 + col];
    else if (g < 27)  v = wm[(g - 18) * 576 + col];
    else if (g < 603) v = wc[(g - 27) * 576 + col];
    Wb[i] = f2bf(v);
  }
  if (i < 64 * 576) {             // Wb2[o][k*64+c] = wconv[o][c*9+k]
    int o = i / 576, r = i - o * 576;
    int kk = r >> 6, c = r & 63;
    Wb2[i] = f2bf(wconv[o * 576 + c * 9 + kk]);
  }
  if (i < 640)
    Bc[i] = (i < 18) ? bp[i] : (i < 27) ? bm[i - 18] : (i < 603) ? bc[i - 27] : 0.f;
}

// ---- K1: fused = 1x1 conv over concat(x, ref) -> PIXEL-MAJOR bf16 fusedt[pix][64] -----
__global__ __launch_bounds__(256) void k_fused(
    const float* __restrict__ x, const float* __restrict__ ref,
    const float* __restrict__ wcd, const float* __restrict__ bcd,
    ushort* __restrict__ fusedt) {
  __shared__ float sw[128 * 64];
  __shared__ float sb[64];
  for (int i = threadIdx.x; i < 128 * 64; i += 256) {
    int ci = i >> 6, o = i & 63;
    sw[i] = wcd[o * 128 + ci];
  }
  if (threadIdx.x < 64) sb[threadIdx.x] = bcd[threadIdx.x];
  __syncthreads();

  int pix = blockIdx.x * 256 + threadIdx.x;
  int b = pix >> 14, hw = pix & 16383;
  const float* xb = x   + ((size_t)b * 64 << 14) + hw;
  const float* rb = ref + ((size_t)b * 64 << 14) + hw;

  float4 acc[16];
  #pragma unroll
  for (int o4 = 0; o4 < 16; o4++)
    acc[o4] = make_float4(sb[4*o4], sb[4*o4+1], sb[4*o4+2], sb[4*o4+3]);

  for (int ci = 0; ci < 64; ci++) {
    float v = xb[(size_t)ci << 14];
    const float4* wr = (const float4*)&sw[ci * 64];
    #pragma unroll
    for (int o4 = 0; o4 < 16; o4++) {
      float4 w4 = wr[o4];
      acc[o4].x += w4.x * v; acc[o4].y += w4.y * v;
      acc[o4].z += w4.z * v; acc[o4].w += w4.w * v;
    }
  }
  for (int ci = 0; ci < 64; ci++) {
    float v = rb[(size_t)ci << 14];
    const float4* wr = (const float4*)&sw[(64 + ci) * 64];
    #pragma unroll
    for (int o4 = 0; o4 < 16; o4++) {
      float4 w4 = wr[o4];
      acc[o4].x += w4.x * v; acc[o4].y += w4.y * v;
      acc[o4].z += w4.z * v; acc[o4].w += w4.w * v;
    }
  }
  ushort vals[64];
  #pragma unroll
  for (int o4 = 0; o4 < 16; o4++) {
    vals[4*o4+0] = f2bf(acc[o4].x); vals[4*o4+1] = f2bf(acc[o4].y);
    vals[4*o4+2] = f2bf(acc[o4].z); vals[4*o4+3] = f2bf(acc[o4].w);
  }
  ushort* fb = fusedt + ((size_t)pix << 6);
  #pragma unroll
  for (int q = 0; q < 8; q++)
    *(uint4*)(fb + q * 8) = *(uint4*)(vals + q * 8);
}

// ---- K2: xt[b][hw][c] fp32 pixel-major transpose of x --------------------------------
__global__ __launch_bounds__(256) void k_xt(
    const float* __restrict__ x, float* __restrict__ xt) {
  __shared__ float sx[64][65];
  const int t = threadIdx.x;
  const int b = blockIdx.x >> 8, hw0 = (blockIdx.x & 255) << 6;
  for (int i = t; i < 4096; i += 256) {
    int c = i >> 6, hwi = i & 63;
    sx[c][hwi] = x[((size_t)(b * 64 + c) << 14) + hw0 + hwi];
  }
  __syncthreads();
  for (int i = t; i < 4096; i += 256) {
    int hwi = i >> 6, c = i & 63;
    xt[(((size_t)b << 14) + hw0 + hwi) * 64 + c] = sx[c][hwi];
  }
}

// ---- K3: DIRECT-CONV MFMA GEMM head = Wb(*)fused, fused bias+act ----------------------
// grid (og 5, rowid 512); block = 4 waves; tile 128oc x 128px (one image row).
// K = 576 reordered kk-major: k = kk*64 + ci. B-fragments built from LDS-staged
// fused rows h-1..h+1 (halo-padded, ci-group rotated by w1 to spread banks).
__global__ __launch_bounds__(256) void k_gemm(
    const ushort* __restrict__ Wb, const ushort* __restrict__ fusedt,
    const float* __restrict__ Bc,
    float* __restrict__ headom, ushort* __restrict__ headcol) {
  __shared__ __align__(16) ushort sF[3 * 130 * 64];   // 49,920 B
  __shared__ __align__(16) ushort sW[128 * 32];       //  8,192 B
  const int t = threadIdx.x;
  const int lane = t & 63, wv = t >> 6;
  const int og = blockIdx.x;              // 0..4
  const int rowid = blockIdx.y;           // b*128 + h
  const int b = rowid >> 7, h = rowid & 127;
  const int hw0 = (rowid << 7) & 16383;
  const ushort* Wrow = Wb + (size_t)(og * 128) * 576;

  // stage fused rows h-1..h+1, w1 in [0,130) covering gw in [-1,128]
  for (int idx = t; idx < 3120; idx += 256) {     // 390 pixels x 8 ci-chunks
    int p = idx >> 3, j = idx & 7;
    int row = p / 130, w1 = p - row * 130;
    int gh = h + row - 1, gw = w1 - 1;
    uint4 v = make_uint4(0u, 0u, 0u, 0u);
    if (gh >= 0 && gh < 128 && (unsigned)gw < 128u)
      v = *(const uint4*)(fusedt + ((size_t)((b << 14) + (gh << 7) + gw) << 6) + j * 8);
    int slot = (j + w1) & 7;
    *(uint4*)(sF + (p << 6) + slot * 8) = v;
  }

  f32x4 acc[4][4];
  #pragma unroll
  for (int mi = 0; mi < 4; mi++)
    #pragma unroll
    for (int ni = 0; ni < 4; ni++) acc[mi][ni] = (f32x4){0.f, 0.f, 0.f, 0.f};

  const int srow = lane >> 2, sslot = lane & 3;
  const int ocq = wv & 1, pxq = wv >> 1;
  const int nif = lane & 15, kb = lane >> 4;

  for (int ks = 0; ks < 18; ks++) {
    const int kk = ks >> 1, half = ks & 1;
    const int k0 = kk * 64 + half * 32;
    const int dr = kk / 3, dc = kk - dr * 3;
    __syncthreads();
    #pragma unroll
    for (int c = 0; c < 2; c++) {
      int row = (wv << 5) + (c << 4) + srow;
      int g = (sslot - (row >> 1)) & 3;
      gload_lds16(Wrow + (size_t)row * 576 + k0 + g * 8,
                  sW + (((wv << 5) + (c << 4)) << 5));
    }
    __syncthreads();

    s16x8 af[4], bfr[4];
    #pragma unroll
    for (int mi = 0; mi < 4; mi++) {
      int m = (ocq << 6) + mi * 16 + nif;
      int s = (kb + (m >> 1)) & 3;
      af[mi] = *(const s16x8*)(sW + m * 32 + s * 8);
    }
    const int gci = half * 4 + kb;        // logical ci-group 0..7
    #pragma unroll
    for (int ni = 0; ni < 4; ni++) {
      int r = (pxq << 6) + ni * 16 + nif;
      int w1 = r + dc;
      int slot = (gci + w1) & 7;
      bfr[ni] = *(const s16x8*)(sF + ((dr * 130 + w1) << 6) + slot * 8);
    }
    #pragma unroll
    for (int mi = 0; mi < 4; mi++)
      #pragma unroll
      for (int ni = 0; ni < 4; ni++)
        acc[mi][ni] = __builtin_amdgcn_mfma_f32_16x16x32_bf16(af[mi], bfr[ni], acc[mi][ni], 0, 0, 0);
  }

  const int quad = lane >> 4;
  #pragma unroll
  for (int mi = 0; mi < 4; mi++) {
    #pragma unroll
    for (int ni = 0; ni < 4; ni++) {
      int hw = hw0 + (pxq << 6) + ni * 16 + nif;
      #pragma unroll
      for (int r = 0; r < 4; r++) {
        int g = og * 128 + (ocq << 6) + mi * 16 + quad * 4 + r;
        float v = acc[mi][ni][r] + Bc[g];
        if (g < 18) {
          headom[(((size_t)b * 27 + g) << 14) + hw] = v;
        } else if (g < 27) {
          headom[(((size_t)b * 27 + g) << 14) + hw] = 1.f / (1.f + expf(-v));
        } else if (g < 603) {
          headcol[(((size_t)b * 576 + (g - 27)) << 14) + hw] = f2bf(tanhf(v));
        }
      }
    }
  }
}

// ---- K5: sampler -> inp bf16 U[pix][k*64+c] -------------------------------------------
__global__ __launch_bounds__(256, 4) void k_samp(
    const float* __restrict__ xt, const float* __restrict__ headom,
    const ushort* __restrict__ headcol, ushort* __restrict__ U) {
  const int t = threadIdx.x;
  const int cq = t >> 6;                      // 0..3 -> channels cq*16 .. +16
  const int pix = blockIdx.x * 64 + (t & 63);
  const int b = pix >> 14, hw = pix & 16383;
  const int h = hw >> 7, w = hw & 127;
  const float* hbom = headom + (((size_t)b * 27) << 14) + hw;
  const float* xb = xt + ((size_t)b << 20);   // xt[b][hw][64]
  const ushort* colb = headcol + (((size_t)b * 576) << 14) + hw;
  ushort* up = U + (size_t)pix * 576 + cq * 16;

  #pragma unroll 1
  for (int k = 0; k < 9; k++) {
    float ox = hbom[(size_t)k << 14];
    float oy = hbom[(size_t)(9 + k) << 14];
    float mk = hbom[(size_t)(18 + k) << 14];
    float px = (float)(h + k / 3) + ox;
    float py = (float)(w + k % 3) + oy;
    float fx = floorf(px), fy = floorf(py);
    float qltx = fminf(fmaxf(fx, 0.f), 129.f);
    float qlty = fminf(fmaxf(fy, 0.f), 129.f);
    float qrbx = fminf(fmaxf(fx + 1.f, 0.f), 129.f);
    float qrby = fminf(fmaxf(fy + 1.f, 0.f), 129.f);
    float sx = fminf(fmaxf(px, 0.f), 129.f);
    float sy = fminf(fmaxf(py, 0.f), 129.f);
    float ax = 1.f + qltx - sx, bx = 1.f - qrbx + sx;
    float ay = 1.f + qlty - sy, by = 1.f - qrby + sy;
    int iltx = (int)qltx, ilty = (int)qlty, irbx = (int)qrbx, irby = (int)qrby;
    bool vltx = (iltx >= 1) && (iltx <= 128);
    bool vlty = (ilty >= 1) && (ilty <= 128);
    bool vrbx = (irbx >= 1) && (irbx <= 128);
    bool vrby = (irby >= 1) && (irby <= 128);
    float wl[4];
    int   ofs[4];
    wl[0] = (vltx && vlty) ? ax * ay : 0.f;
    wl[1] = (vrbx && vrby) ? bx * by : 0.f;
    wl[2] = (vltx && vrby) ? ax * by : 0.f;
    wl[3] = (vrbx && vlty) ? bx * ay : 0.f;
    ofs[0] = (vltx && vlty) ? ((iltx - 1) << 7) + (ilty - 1) : 0;
    ofs[1] = (vrbx && vrby) ? ((irbx - 1) << 7) + (irby - 1) : 0;
    ofs[2] = (vltx && vrby) ? ((iltx - 1) << 7) + (irby - 1) : 0;
    ofs[3] = (vrbx && vlty) ? ((irbx - 1) << 7) + (ilty - 1) : 0;

    float pos[16];
    #pragma unroll
    for (int j = 0; j < 16; j++) pos[j] = 0.f;
    #pragma unroll
    for (int corner = 0; corner < 4; corner++) {
      const float* p = xb + ((size_t)ofs[corner] << 6) + cq * 16;
      float wgt = wl[corner];
      #pragma unroll
      for (int q = 0; q < 4; q++) {
        float4 v = *(const float4*)(p + 4 * q);
        pos[4*q+0] += wgt * v.x; pos[4*q+1] += wgt * v.y;
        pos[4*q+2] += wgt * v.z; pos[4*q+3] += wgt * v.w;
      }
    }
    ushort vals[16];
    #pragma unroll
    for (int j = 0; j < 16; j++) {
      float col = bf2f(colb[(size_t)((cq * 16 + j) * 9 + k) << 14]);
      vals[j] = f2bf((col + pos[j]) * mk);
    }
    *(uint4*)(up + k * 64)     = *(uint4*)(vals);
    *(uint4*)(up + k * 64 + 8) = *(uint4*)(vals + 8);
  }
}

// ---- K6: MFMA GEMM out[64][pix] = Wb2 x U^T (both K-permuted consistently) ------------
__global__ __launch_bounds__(256) void k_out(
    const ushort* __restrict__ W2, const ushort* __restrict__ U,
    float* __restrict__ out) {
  __shared__ __align__(16) ushort sW[64 * 32];
  __shared__ __align__(16) ushort sP[256 * 32];
  const int t = threadIdx.x;
  const int lane = t & 63, wv = t >> 6;
  const int m0 = blockIdx.x * 256;
  const int bb = m0 >> 14, hw0 = m0 & 16383;

  f32x4 acc[4][4];
  #pragma unroll
  for (int mi = 0; mi < 4; mi++)
    #pragma unroll
    for (int ni = 0; ni < 4; ni++) acc[mi][ni] = (f32x4){0.f, 0.f, 0.f, 0.f};

  const int srow = lane >> 2, sslot = lane & 3;

  for (int ks = 0; ks < 18; ks++) {
    const int k0 = ks * 32;
    __syncthreads();
    {
      int row = (wv << 4) + srow;
      int g = (sslot - (row >> 1)) & 3;
      gload_lds16(W2 + (size_t)row * 576 + k0 + g * 8, sW + (wv << 9));
    }
    #pragma unroll
    for (int c = 0; c < 4; c++) {
      int prow = (wv << 6) + (c << 4) + srow;
      int g = (sslot - (prow >> 1)) & 3;
      gload_lds16(U + (size_t)(m0 + prow) * 576 + k0 + g * 8,
                  sP + (((wv << 6) + (c << 4)) << 5));
    }
    __syncthreads();

    const int nif = lane & 15, kb = lane >> 4;
    s16x8 af[4], bfr[4];
    #pragma unroll
    for (int mi = 0; mi < 4; mi++) {
      int m = mi * 16 + nif;
      int s = (kb + (m >> 1)) & 3;
      af[mi] = *(const s16x8*)(sW + m * 32 + s * 8);
    }
    #pragma unroll
    for (int ni = 0; ni < 4; ni++) {
      int r = (wv << 6) + ni * 16 + nif;
      int s = (kb + (r >> 1)) & 3;
      bfr[ni] = *(const s16x8*)(sP + r * 32 + s * 8);
    }
    #pragma unroll
    for (int mi = 0; mi < 4; mi++)
      #pragma unroll
      for (int ni = 0; ni < 4; ni++)
        acc[mi][ni] = __builtin_amdgcn_mfma_f32_16x16x32_bf16(af[mi], bfr[ni], acc[mi][ni], 0, 0, 0);
  }

  const int nif = lane & 15, quad = lane >> 4;
  #pragma unroll
  for (int mi = 0; mi < 4; mi++) {
    #pragma unroll
    for (int ni = 0; ni < 4; ni++) {
      int hw = hw0 + (wv << 6) + ni * 16 + nif;
      #pragma unroll
      for (int r = 0; r < 4; r++) {
        int g = mi * 16 + quad * 4 + r;
        out[(((size_t)bb * 64 + g) << 14) + hw] = acc[mi][ni][r];
      }
    }
  }
}

extern "C" void kernel_launch(void* const* d_in, const int* in_sizes, int n_in,
                              void* d_out, int out_size, void* d_ws, size_t ws_size,
                              hipStream_t stream) {
  const float* x     = (const float*)d_in[0];
  const float* ref   = (const float*)d_in[1];
  const float* wcd   = (const float*)d_in[2];
  const float* bcd   = (const float*)d_in[3];
  const float* wp    = (const float*)d_in[4];
  const float* bp    = (const float*)d_in[5];
  const float* wm    = (const float*)d_in[6];
  const float* bm    = (const float*)d_in[7];
  const float* wc    = (const float*)d_in[8];
  const float* bc    = (const float*)d_in[9];
  const float* wconv = (const float*)d_in[10];
  float* out = (float*)d_out;

  char* w8 = (char*)d_ws;
  ushort* Wb      = (ushort*)(w8 + 0);           //    737,280 B
  float*  Bc      = (float*)(w8 + 737280);       //      2,560 B
  ushort* Wb2     = (ushort*)(w8 + 739840);      //     73,728 B
  ushort* fusedt  = (ushort*)(w8 + 813568);      //  8,388,608 B (pixel-major)
  ushort* U       = (ushort*)(w8 + 9202176);     // 75,497,472 B
  float*  headom  = (float*)(w8 + 84699648);     //  7,077,888 B
  ushort* headcol = (ushort*)(w8 + 91777536);    // 75,497,472 B
  float*  xt      = (float*)(w8 + 167275008);    // 16,777,216 B -> total 184,052,224 B

  k_merge <<<1440, 256, 0, stream>>>(wp, bp, wm, bm, wc, bc, wconv, Wb, Bc, Wb2);
  k_fused <<<256, 256, 0, stream>>>(x, ref, wcd, bcd, fusedt);
  k_xt    <<<1024, 256, 0, stream>>>(x, xt);
  k_gemm  <<<dim3(5, 512), 256, 0, stream>>>(Wb, fusedt, Bc, headom, headcol);
  k_samp  <<<1024, 256, 0, stream>>>(xt, headom, headcol, U);
  k_out   <<<256, 256, 0, stream>>>(Wb2, U, out);
}

// Round 7
// 442.026 us; speedup vs baseline: 1.0268x; 1.0268x over previous
//
#include <hip/hip_runtime.h>
#include <math.h>

typedef short s16x8 __attribute__((ext_vector_type(8)));
typedef float f32x4 __attribute__((ext_vector_type(4)));

__device__ inline ushort f2bf(float f) {
  unsigned u = __float_as_uint(f);
  u = (u + 0x7FFF + ((u >> 16) & 1)) >> 16;
  return (ushort)u;
}
__device__ inline float bf2f(ushort u) {
  return __uint_as_float(((unsigned)u) << 16);
}
__device__ inline void gload_lds16(const void* g, void* l) {
  __builtin_amdgcn_global_load_lds(
      (const __attribute__((address_space(1))) unsigned*)g,
      (__attribute__((address_space(3))) unsigned*)l, 16, 0, 0);
}

// ---- K0: pack weights into MFMA-fragment order ----------------------------------------
// Wpk[og 5][ks 18][ocq 2][mi 4][lane 64][e 8]: af[mi] for (og,ks,ocq,lane) is contiguous.
//   g = og*128+ocq*64+mi*16+(lane&15); ci = (ks&1)*32+(lane>>4)*8+e; kk = ks>>1.
// W2pk[ks 18][mi 4][lane 64][e 8]: o = mi*16+(lane&15); p = ks*32+(lane>>4)*8+e;
//   kk = p>>6, c = p&63 (k-major permuted axis), orig col = c*9+kk.
__global__ __launch_bounds__(256) void k_merge(
    const float* __restrict__ wp, const float* __restrict__ bp,
    const float* __restrict__ wm, const float* __restrict__ bm,
    const float* __restrict__ wc, const float* __restrict__ bc,
    const float* __restrict__ wconv,
    ushort* __restrict__ Wpk, float* __restrict__ Bc, ushort* __restrict__ W2pk) {
  int i = blockIdx.x * 256 + threadIdx.x;
  if (i < 368640) {
    int e = i & 7, lane = (i >> 3) & 63, mi = (i >> 9) & 3, ocq = (i >> 11) & 1;
    int hi = i >> 12;                 // 0..89
    int ks = hi % 18, og = hi / 18;
    int g = og * 128 + ocq * 64 + mi * 16 + (lane & 15);
    int ci = ((ks & 1) << 5) + ((lane >> 4) << 3) + e;
    int kk = ks >> 1;
    int col = ci * 9 + kk;
    float v = 0.f;
    if (g < 18)       v = wp[g * 576 + col];
    else if (g < 27)  v = wm[(g - 18) * 576 + col];
    else if (g < 603) v = wc[(g - 27) * 576 + col];
    Wpk[i] = f2bf(v);
  }
  if (i < 36864) {
    int e = i & 7, lane = (i >> 3) & 63, mi = (i >> 9) & 3, ks = i >> 11;  // 0..17
    int o = mi * 16 + (lane & 15);
    int p = (ks << 5) + ((lane >> 4) << 3) + e;
    int kk2 = p >> 6, c = p & 63;
    W2pk[i] = f2bf(wconv[o * 576 + c * 9 + kk2]);
  }
  if (i < 640)
    Bc[i] = (i < 18) ? bp[i] : (i < 27) ? bm[i - 18] : (i < 603) ? bc[i - 27] : 0.f;
}

// ---- K1: fused = 1x1 conv over concat(x, ref) -> PIXEL-MAJOR bf16 fusedt[pix][64] -----
__global__ __launch_bounds__(256) void k_fused(
    const float* __restrict__ x, const float* __restrict__ ref,
    const float* __restrict__ wcd, const float* __restrict__ bcd,
    ushort* __restrict__ fusedt) {
  __shared__ float sw[128 * 64];
  __shared__ float sb[64];
  for (int i = threadIdx.x; i < 128 * 64; i += 256) {
    int ci = i >> 6, o = i & 63;
    sw[i] = wcd[o * 128 + ci];
  }
  if (threadIdx.x < 64) sb[threadIdx.x] = bcd[threadIdx.x];
  __syncthreads();

  int pix = blockIdx.x * 256 + threadIdx.x;
  int b = pix >> 14, hw = pix & 16383;
  const float* xb = x   + ((size_t)b * 64 << 14) + hw;
  const float* rb = ref + ((size_t)b * 64 << 14) + hw;

  float4 acc[16];
  #pragma unroll
  for (int o4 = 0; o4 < 16; o4++)
    acc[o4] = make_float4(sb[4*o4], sb[4*o4+1], sb[4*o4+2], sb[4*o4+3]);

  for (int ci = 0; ci < 64; ci++) {
    float v = xb[(size_t)ci << 14];
    const float4* wr = (const float4*)&sw[ci * 64];
    #pragma unroll
    for (int o4 = 0; o4 < 16; o4++) {
      float4 w4 = wr[o4];
      acc[o4].x += w4.x * v; acc[o4].y += w4.y * v;
      acc[o4].z += w4.z * v; acc[o4].w += w4.w * v;
    }
  }
  for (int ci = 0; ci < 64; ci++) {
    float v = rb[(size_t)ci << 14];
    const float4* wr = (const float4*)&sw[(64 + ci) * 64];
    #pragma unroll
    for (int o4 = 0; o4 < 16; o4++) {
      float4 w4 = wr[o4];
      acc[o4].x += w4.x * v; acc[o4].y += w4.y * v;
      acc[o4].z += w4.z * v; acc[o4].w += w4.w * v;
    }
  }
  ushort vals[64];
  #pragma unroll
  for (int o4 = 0; o4 < 16; o4++) {
    vals[4*o4+0] = f2bf(acc[o4].x); vals[4*o4+1] = f2bf(acc[o4].y);
    vals[4*o4+2] = f2bf(acc[o4].z); vals[4*o4+3] = f2bf(acc[o4].w);
  }
  ushort* fb = fusedt + ((size_t)pix << 6);
  #pragma unroll
  for (int q = 0; q < 8; q++)
    *(uint4*)(fb + q * 8) = *(uint4*)(vals + q * 8);
}

// ---- K2: xt[b][hw][c] fp32 pixel-major transpose of x --------------------------------
__global__ __launch_bounds__(256) void k_xt(
    const float* __restrict__ x, float* __restrict__ xt) {
  __shared__ float sx[64][65];
  const int t = threadIdx.x;
  const int b = blockIdx.x >> 8, hw0 = (blockIdx.x & 255) << 6;
  for (int i = t; i < 4096; i += 256) {
    int c = i >> 6, hwi = i & 63;
    sx[c][hwi] = x[((size_t)(b * 64 + c) << 14) + hw0 + hwi];
  }
  __syncthreads();
  for (int i = t; i < 4096; i += 256) {
    int hwi = i >> 6, c = i & 63;
    xt[(((size_t)b << 14) + hw0 + hwi) * 64 + c] = sx[c][hwi];
  }
}

// ---- K3: DIRECT-CONV MFMA GEMM head = W(*)fused, barrier-free K-loop ------------------
// grid (og 5, rowid 512); block = 4 waves; tile 128oc x 128px (one image row).
// A-fragments straight from packed-global Wpk (coalesced, L2-hot); B-fragments from
// LDS-staged fused rows h-1..h+1 (staged ONCE, single barrier).
__global__ __launch_bounds__(256) void k_gemm(
    const ushort* __restrict__ Wpk, const ushort* __restrict__ fusedt,
    const float* __restrict__ Bc,
    float* __restrict__ headom, ushort* __restrict__ headcol) {
  __shared__ __align__(16) ushort sF[3 * 130 * 64];   // 49,920 B
  const int t = threadIdx.x;
  const int lane = t & 63, wv = t >> 6;
  const int og = blockIdx.x;              // 0..4
  const int rowid = blockIdx.y;           // b*128 + h
  const int b = rowid >> 7, h = rowid & 127;
  const int hw0 = (rowid << 7) & 16383;

  // stage fused rows h-1..h+1, w1 in [0,130) covering gw in [-1,128]
  for (int idx = t; idx < 3120; idx += 256) {     // 390 pixels x 8 ci-chunks
    int p = idx >> 3, j = idx & 7;
    int row = p / 130, w1 = p - row * 130;
    int gh = h + row - 1, gw = w1 - 1;
    uint4 v = make_uint4(0u, 0u, 0u, 0u);
    if (gh >= 0 && gh < 128 && (unsigned)gw < 128u)
      v = *(const uint4*)(fusedt + ((size_t)((b << 14) + (gh << 7) + gw) << 6) + j * 8);
    int slot = (j + w1) & 7;
    *(uint4*)(sF + (p << 6) + slot * 8) = v;
  }
  __syncthreads();

  f32x4 acc[4][4];
  #pragma unroll
  for (int mi = 0; mi < 4; mi++)
    #pragma unroll
    for (int ni = 0; ni < 4; ni++) acc[mi][ni] = (f32x4){0.f, 0.f, 0.f, 0.f};

  const int ocq = wv & 1, pxq = wv >> 1;
  const int nif = lane & 15, kb = lane >> 4;

  #pragma unroll 2
  for (int ks = 0; ks < 18; ks++) {
    const int kk = ks >> 1, half = ks & 1;
    const int dr = kk / 3, dc = kk - dr * 3;
    const ushort* wp8 = Wpk + ((size_t)((((og * 18 + ks) << 1) + ocq) << 11)) + (lane << 3);
    s16x8 af[4], bfr[4];
    #pragma unroll
    for (int mi = 0; mi < 4; mi++)
      af[mi] = *(const s16x8*)(wp8 + (mi << 9));
    const int gci = half * 4 + kb;        // logical ci-group 0..7
    #pragma unroll
    for (int ni = 0; ni < 4; ni++) {
      int r = (pxq << 6) + ni * 16 + nif;
      int w1 = r + dc;
      int slot = (gci + w1) & 7;
      bfr[ni] = *(const s16x8*)(sF + ((dr * 130 + w1) << 6) + slot * 8);
    }
    #pragma unroll
    for (int mi = 0; mi < 4; mi++)
      #pragma unroll
      for (int ni = 0; ni < 4; ni++)
        acc[mi][ni] = __builtin_amdgcn_mfma_f32_16x16x32_bf16(af[mi], bfr[ni], acc[mi][ni], 0, 0, 0);
  }

  const int quad = lane >> 4;
  #pragma unroll
  for (int mi = 0; mi < 4; mi++) {
    #pragma unroll
    for (int ni = 0; ni < 4; ni++) {
      int hw = hw0 + (pxq << 6) + ni * 16 + nif;
      #pragma unroll
      for (int r = 0; r < 4; r++) {
        int g = og * 128 + (ocq << 6) + mi * 16 + quad * 4 + r;
        float v = acc[mi][ni][r] + Bc[g];
        if (g < 18) {
          headom[(((size_t)b * 27 + g) << 14) + hw] = v;
        } else if (g < 27) {
          headom[(((size_t)b * 27 + g) << 14) + hw] = 1.f / (1.f + expf(-v));
        } else if (g < 603) {
          headcol[(((size_t)b * 576 + (g - 27)) << 14) + hw] = f2bf(tanhf(v));
        }
      }
    }
  }
}

// ---- K5: sampler -> inp bf16 U[pix][k*64+c] -------------------------------------------
__global__ __launch_bounds__(256, 4) void k_samp(
    const float* __restrict__ xt, const float* __restrict__ headom,
    const ushort* __restrict__ headcol, ushort* __restrict__ U) {
  const int t = threadIdx.x;
  const int cq = t >> 6;                      // 0..3 -> channels cq*16 .. +16
  const int pix = blockIdx.x * 64 + (t & 63);
  const int b = pix >> 14, hw = pix & 16383;
  const int h = hw >> 7, w = hw & 127;
  const float* hbom = headom + (((size_t)b * 27) << 14) + hw;
  const float* xb = xt + ((size_t)b << 20);   // xt[b][hw][64]
  const ushort* colb = headcol + (((size_t)b * 576) << 14) + hw;
  ushort* up = U + (size_t)pix * 576 + cq * 16;

  #pragma unroll 1
  for (int k = 0; k < 9; k++) {
    float ox = hbom[(size_t)k << 14];
    float oy = hbom[(size_t)(9 + k) << 14];
    float mk = hbom[(size_t)(18 + k) << 14];
    float px = (float)(h + k / 3) + ox;
    float py = (float)(w + k % 3) + oy;
    float fx = floorf(px), fy = floorf(py);
    float qltx = fminf(fmaxf(fx, 0.f), 129.f);
    float qlty = fminf(fmaxf(fy, 0.f), 129.f);
    float qrbx = fminf(fmaxf(fx + 1.f, 0.f), 129.f);
    float qrby = fminf(fmaxf(fy + 1.f, 0.f), 129.f);
    float sx = fminf(fmaxf(px, 0.f), 129.f);
    float sy = fminf(fmaxf(py, 0.f), 129.f);
    float ax = 1.f + qltx - sx, bx = 1.f - qrbx + sx;
    float ay = 1.f + qlty - sy, by = 1.f - qrby + sy;
    int iltx = (int)qltx, ilty = (int)qlty, irbx = (int)qrbx, irby = (int)qrby;
    bool vltx = (iltx >= 1) && (iltx <= 128);
    bool vlty = (ilty >= 1) && (ilty <= 128);
    bool vrbx = (irbx >= 1) && (irbx <= 128);
    bool vrby = (irby >= 1) && (irby <= 128);
    float wl[4];
    int   ofs[4];
    wl[0] = (vltx && vlty) ? ax * ay : 0.f;
    wl[1] = (vrbx && vrby) ? bx * by : 0.f;
    wl[2] = (vltx && vrby) ? ax * by : 0.f;
    wl[3] = (vrbx && vlty) ? bx * ay : 0.f;
    ofs[0] = (vltx && vlty) ? ((iltx - 1) << 7) + (ilty - 1) : 0;
    ofs[1] = (vrbx && vrby) ? ((irbx - 1) << 7) + (irby - 1) : 0;
    ofs[2] = (vltx && vrby) ? ((iltx - 1) << 7) + (irby - 1) : 0;
    ofs[3] = (vrbx && vlty) ? ((irbx - 1) << 7) + (ilty - 1) : 0;

    float pos[16];
    #pragma unroll
    for (int j = 0; j < 16; j++) pos[j] = 0.f;
    #pragma unroll
    for (int corner = 0; corner < 4; corner++) {
      const float* p = xb + ((size_t)ofs[corner] << 6) + cq * 16;
      float wgt = wl[corner];
      #pragma unroll
      for (int q = 0; q < 4; q++) {
        float4 v = *(const float4*)(p + 4 * q);
        pos[4*q+0] += wgt * v.x; pos[4*q+1] += wgt * v.y;
        pos[4*q+2] += wgt * v.z; pos[4*q+3] += wgt * v.w;
      }
    }
    ushort vals[16];
    #pragma unroll
    for (int j = 0; j < 16; j++) {
      float col = bf2f(colb[(size_t)((cq * 16 + j) * 9 + k) << 14]);
      vals[j] = f2bf((col + pos[j]) * mk);
    }
    *(uint4*)(up + k * 64)     = *(uint4*)(vals);
    *(uint4*)(up + k * 64 + 8) = *(uint4*)(vals + 8);
  }
}

// ---- K6: MFMA GEMM out[64][pix] = W2 x U^T; packed-global af + double-buffered sP -----
__global__ __launch_bounds__(256) void k_out(
    const ushort* __restrict__ W2pk, const ushort* __restrict__ U,
    float* __restrict__ out) {
  __shared__ __align__(16) ushort sP[2 * 256 * 32];   // 32 KB
  const int t = threadIdx.x;
  const int lane = t & 63, wv = t >> 6;
  const int m0 = blockIdx.x * 256;
  const int bb = m0 >> 14, hw0 = m0 & 16383;
  const int srow = lane >> 2, sslot = lane & 3;
  const int nif = lane & 15, kb = lane >> 4;

  f32x4 acc[4][4];
  #pragma unroll
  for (int mi = 0; mi < 4; mi++)
    #pragma unroll
    for (int ni = 0; ni < 4; ni++) acc[mi][ni] = (f32x4){0.f, 0.f, 0.f, 0.f};

  // stage(buf, ks): wave wv stages pixel rows [wv*64, wv*64+64)
  #define STAGE(buf, ksv)                                                      \
    {                                                                          \
      _Pragma("unroll")                                                        \
      for (int c = 0; c < 4; c++) {                                            \
        int prow = (wv << 6) + (c << 4) + srow;                                \
        int g = (sslot - (prow >> 1)) & 3;                                     \
        gload_lds16(U + (size_t)(m0 + prow) * 576 + (ksv) * 32 + g * 8,        \
                    sP + ((buf) << 13) + (((wv << 6) + (c << 4)) << 5));       \
      }                                                                        \
    }

  STAGE(0, 0)
  for (int ks = 0; ks < 18; ks++) {
    __syncthreads();
    if (ks < 17) STAGE((ks + 1) & 1, ks + 1)
    const ushort* base = sP + ((ks & 1) << 13);
    s16x8 af[4], bfr[4];
    #pragma unroll
    for (int mi = 0; mi < 4; mi++)
      af[mi] = *(const s16x8*)(W2pk + ((((ks << 2) + mi) << 6) + lane) * 8);
    #pragma unroll
    for (int ni = 0; ni < 4; ni++) {
      int r = (wv << 6) + ni * 16 + nif;
      int s = (kb + (r >> 1)) & 3;
      bfr[ni] = *(const s16x8*)(base + r * 32 + s * 8);
    }
    #pragma unroll
    for (int mi = 0; mi < 4; mi++)
      #pragma unroll
      for (int ni = 0; ni < 4; ni++)
        acc[mi][ni] = __builtin_amdgcn_mfma_f32_16x16x32_bf16(af[mi], bfr[ni], acc[mi][ni], 0, 0, 0);
  }
  #undef STAGE

  const int quad = lane >> 4;
  #pragma unroll
  for (int mi = 0; mi < 4; mi++) {
    #pragma unroll
    for (int ni = 0; ni < 4; ni++) {
      int hw = hw0 + (wv << 6) + ni * 16 + nif;
      #pragma unroll
      for (int r = 0; r < 4; r++) {
        int g = mi * 16 + quad * 4 + r;
        out[(((size_t)bb * 64 + g) << 14) + hw] = acc[mi][ni][r];
      }
    }
  }
}

extern "C" void kernel_launch(void* const* d_in, const int* in_sizes, int n_in,
                              void* d_out, int out_size, void* d_ws, size_t ws_size,
                              hipStream_t stream) {
  const float* x     = (const float*)d_in[0];
  const float* ref   = (const float*)d_in[1];
  const float* wcd   = (const float*)d_in[2];
  const float* bcd   = (const float*)d_in[3];
  const float* wp    = (const float*)d_in[4];
  const float* bp    = (const float*)d_in[5];
  const float* wm    = (const float*)d_in[6];
  const float* bm    = (const float*)d_in[7];
  const float* wc    = (const float*)d_in[8];
  const float* bc    = (const float*)d_in[9];
  const float* wconv = (const float*)d_in[10];
  float* out = (float*)d_out;

  char* w8 = (char*)d_ws;
  ushort* Wpk     = (ushort*)(w8 + 0);           //    737,280 B
  float*  Bc      = (float*)(w8 + 737280);       //      2,560 B
  ushort* W2pk    = (ushort*)(w8 + 739840);      //     73,728 B
  ushort* fusedt  = (ushort*)(w8 + 813568);      //  8,388,608 B (pixel-major)
  ushort* U       = (ushort*)(w8 + 9202176);     // 75,497,472 B
  float*  headom  = (float*)(w8 + 84699648);     //  7,077,888 B
  ushort* headcol = (ushort*)(w8 + 91777536);    // 75,497,472 B
  float*  xt      = (float*)(w8 + 167275008);    // 16,777,216 B -> total 184,052,224 B

  k_merge <<<1440, 256, 0, stream>>>(wp, bp, wm, bm, wc, bc, wconv, Wpk, Bc, W2pk);
  k_fused <<<256, 256, 0, stream>>>(x, ref, wcd, bcd, fusedt);
  k_xt    <<<1024, 256, 0, stream>>>(x, xt);
  k_gemm  <<<dim3(5, 512), 256, 0, stream>>>(Wpk, fusedt, Bc, headom, headcol);
  k_samp  <<<1024, 256, 0, stream>>>(xt, headom, headcol, U);
  k_out   <<<256, 256, 0, stream>>>(W2pk, U, out);
}

// Round 8
// 391.434 us; speedup vs baseline: 1.1595x; 1.1292x over previous
//
#include <hip/hip_runtime.h>
#include <math.h>

typedef short s16x8 __attribute__((ext_vector_type(8)));
typedef float f32x4 __attribute__((ext_vector_type(4)));

__device__ inline ushort f2bf(float f) {
  unsigned u = __float_as_uint(f);
  u = (u + 0x7FFF + ((u >> 16) & 1)) >> 16;
  return (ushort)u;
}
__device__ inline float bf2f(ushort u) {
  return __uint_as_float(((unsigned)u) << 16);
}
__device__ inline void gload_lds16(const void* g, void* l) {
  __builtin_amdgcn_global_load_lds(
      (const __attribute__((address_space(1))) unsigned*)g,
      (__attribute__((address_space(3))) unsigned*)l, 16, 0, 0);
}
// fast activations: v_exp_f32 + v_rcp_f32; saturate correctly at +/-inf.
__device__ inline float fast_tanh(float v) {
  float e = __builtin_amdgcn_exp2f(v * 2.8853900817779268f);   // exp(2v)
  return 1.f - 2.f * __builtin_amdgcn_rcpf(e + 1.f);
}
__device__ inline float fast_sigmoid(float v) {
  float e = __builtin_amdgcn_exp2f(v * -1.4426950408889634f);  // exp(-v)
  return __builtin_amdgcn_rcpf(1.f + e);
}

// ---- K0: pack weights into MFMA-fragment order ----------------------------------------
// Wpk[og 5][ks 18][ocq 2][mi 4][lane 64][e 8]: af[mi] for (og,ks,ocq,lane) is contiguous.
//   g = og*128+ocq*64+mi*16+(lane&15); ci = (ks&1)*32+(lane>>4)*8+e; kk = ks>>1.
// W2pk[ks 18][mi 4][lane 64][e 8]: o = mi*16+(lane&15); p = ks*32+(lane>>4)*8+e;
//   kk = p>>6, c = p&63 (k-major permuted axis), orig col = c*9+kk.
__global__ __launch_bounds__(256) void k_merge(
    const float* __restrict__ wp, const float* __restrict__ bp,
    const float* __restrict__ wm, const float* __restrict__ bm,
    const float* __restrict__ wc, const float* __restrict__ bc,
    const float* __restrict__ wconv,
    ushort* __restrict__ Wpk, float* __restrict__ Bc, ushort* __restrict__ W2pk) {
  int i = blockIdx.x * 256 + threadIdx.x;
  if (i < 368640) {
    int e = i & 7, lane = (i >> 3) & 63, mi = (i >> 9) & 3, ocq = (i >> 11) & 1;
    int hi = i >> 12;                 // 0..89
    int ks = hi % 18, og = hi / 18;
    int g = og * 128 + ocq * 64 + mi * 16 + (lane & 15);
    int ci = ((ks & 1) << 5) + ((lane >> 4) << 3) + e;
    int kk = ks >> 1;
    int col = ci * 9 + kk;
    float v = 0.f;
    if (g < 18)       v = wp[g * 576 + col];
    else if (g < 27)  v = wm[(g - 18) * 576 + col];
    else if (g < 603) v = wc[(g - 27) * 576 + col];
    Wpk[i] = f2bf(v);
  }
  if (i < 36864) {
    int e = i & 7, lane = (i >> 3) & 63, mi = (i >> 9) & 3, ks = i >> 11;  // 0..17
    int o = mi * 16 + (lane & 15);
    int p = (ks << 5) + ((lane >> 4) << 3) + e;
    int kk2 = p >> 6, c = p & 63;
    W2pk[i] = f2bf(wconv[o * 576 + c * 9 + kk2]);
  }
  if (i < 640)
    Bc[i] = (i < 18) ? bp[i] : (i < 27) ? bm[i - 18] : (i < 603) ? bc[i - 27] : 0.f;
}

// ---- K1: fused = 1x1 conv over concat(x, ref) -> PIXEL-MAJOR bf16 fusedt[pix][64] -----
__global__ __launch_bounds__(256) void k_fused(
    const float* __restrict__ x, const float* __restrict__ ref,
    const float* __restrict__ wcd, const float* __restrict__ bcd,
    ushort* __restrict__ fusedt) {
  __shared__ float sw[128 * 64];
  __shared__ float sb[64];
  for (int i = threadIdx.x; i < 128 * 64; i += 256) {
    int ci = i >> 6, o = i & 63;
    sw[i] = wcd[o * 128 + ci];
  }
  if (threadIdx.x < 64) sb[threadIdx.x] = bcd[threadIdx.x];
  __syncthreads();

  int pix = blockIdx.x * 256 + threadIdx.x;
  int b = pix >> 14, hw = pix & 16383;
  const float* xb = x   + ((size_t)b * 64 << 14) + hw;
  const float* rb = ref + ((size_t)b * 64 << 14) + hw;

  float4 acc[16];
  #pragma unroll
  for (int o4 = 0; o4 < 16; o4++)
    acc[o4] = make_float4(sb[4*o4], sb[4*o4+1], sb[4*o4+2], sb[4*o4+3]);

  for (int ci = 0; ci < 64; ci++) {
    float v = xb[(size_t)ci << 14];
    const float4* wr = (const float4*)&sw[ci * 64];
    #pragma unroll
    for (int o4 = 0; o4 < 16; o4++) {
      float4 w4 = wr[o4];
      acc[o4].x += w4.x * v; acc[o4].y += w4.y * v;
      acc[o4].z += w4.z * v; acc[o4].w += w4.w * v;
    }
  }
  for (int ci = 0; ci < 64; ci++) {
    float v = rb[(size_t)ci << 14];
    const float4* wr = (const float4*)&sw[(64 + ci) * 64];
    #pragma unroll
    for (int o4 = 0; o4 < 16; o4++) {
      float4 w4 = wr[o4];
      acc[o4].x += w4.x * v; acc[o4].y += w4.y * v;
      acc[o4].z += w4.z * v; acc[o4].w += w4.w * v;
    }
  }
  ushort vals[64];
  #pragma unroll
  for (int o4 = 0; o4 < 16; o4++) {
    vals[4*o4+0] = f2bf(acc[o4].x); vals[4*o4+1] = f2bf(acc[o4].y);
    vals[4*o4+2] = f2bf(acc[o4].z); vals[4*o4+3] = f2bf(acc[o4].w);
  }
  ushort* fb = fusedt + ((size_t)pix << 6);
  #pragma unroll
  for (int q = 0; q < 8; q++)
    *(uint4*)(fb + q * 8) = *(uint4*)(vals + q * 8);
}

// ---- K2: xtb[b][hw][c] bf16 pixel-major transpose of x -------------------------------
__global__ __launch_bounds__(256) void k_xt(
    const float* __restrict__ x, ushort* __restrict__ xtb) {
  __shared__ float sx[64][65];
  const int t = threadIdx.x;
  const int b = blockIdx.x >> 8, hw0 = (blockIdx.x & 255) << 6;
  for (int i = t; i < 4096; i += 256) {
    int c = i >> 6, hwi = i & 63;
    sx[c][hwi] = x[((size_t)(b * 64 + c) << 14) + hw0 + hwi];
  }
  __syncthreads();
  for (int i = t; i < 4096; i += 256) {
    int hwi = i >> 6, c = i & 63;
    xtb[(((size_t)b << 14) + hw0 + hwi) * 64 + c] = f2bf(sx[c][hwi]);
  }
}

// ---- K3: DIRECT-CONV MFMA GEMM head = W(*)fused, barrier-free K-loop ------------------
__global__ __launch_bounds__(256) void k_gemm(
    const ushort* __restrict__ Wpk, const ushort* __restrict__ fusedt,
    const float* __restrict__ Bc,
    float* __restrict__ headom, ushort* __restrict__ headcol) {
  __shared__ __align__(16) ushort sF[3 * 130 * 64];   // 49,920 B
  const int t = threadIdx.x;
  const int lane = t & 63, wv = t >> 6;
  const int og = blockIdx.x;              // 0..4
  const int rowid = blockIdx.y;           // b*128 + h
  const int b = rowid >> 7, h = rowid & 127;
  const int hw0 = (rowid << 7) & 16383;

  // stage fused rows h-1..h+1, w1 in [0,130) covering gw in [-1,128]
  for (int idx = t; idx < 3120; idx += 256) {     // 390 pixels x 8 ci-chunks
    int p = idx >> 3, j = idx & 7;
    int row = p / 130, w1 = p - row * 130;
    int gh = h + row - 1, gw = w1 - 1;
    uint4 v = make_uint4(0u, 0u, 0u, 0u);
    if (gh >= 0 && gh < 128 && (unsigned)gw < 128u)
      v = *(const uint4*)(fusedt + ((size_t)((b << 14) + (gh << 7) + gw) << 6) + j * 8);
    int slot = (j + w1) & 7;
    *(uint4*)(sF + (p << 6) + slot * 8) = v;
  }
  __syncthreads();

  f32x4 acc[4][4];
  #pragma unroll
  for (int mi = 0; mi < 4; mi++)
    #pragma unroll
    for (int ni = 0; ni < 4; ni++) acc[mi][ni] = (f32x4){0.f, 0.f, 0.f, 0.f};

  const int ocq = wv & 1, pxq = wv >> 1;
  const int nif = lane & 15, kb = lane >> 4;

  #pragma unroll 2
  for (int ks = 0; ks < 18; ks++) {
    const int kk = ks >> 1, half = ks & 1;
    const int dr = kk / 3, dc = kk - dr * 3;
    const ushort* wp8 = Wpk + ((size_t)((((og * 18 + ks) << 1) + ocq) << 11)) + (lane << 3);
    s16x8 af[4], bfr[4];
    #pragma unroll
    for (int mi = 0; mi < 4; mi++)
      af[mi] = *(const s16x8*)(wp8 + (mi << 9));
    const int gci = half * 4 + kb;        // logical ci-group 0..7
    #pragma unroll
    for (int ni = 0; ni < 4; ni++) {
      int r = (pxq << 6) + ni * 16 + nif;
      int w1 = r + dc;
      int slot = (gci + w1) & 7;
      bfr[ni] = *(const s16x8*)(sF + ((dr * 130 + w1) << 6) + slot * 8);
    }
    #pragma unroll
    for (int mi = 0; mi < 4; mi++)
      #pragma unroll
      for (int ni = 0; ni < 4; ni++)
        acc[mi][ni] = __builtin_amdgcn_mfma_f32_16x16x32_bf16(af[mi], bfr[ni], acc[mi][ni], 0, 0, 0);
  }

  const int quad = lane >> 4;
  #pragma unroll
  for (int mi = 0; mi < 4; mi++) {
    #pragma unroll
    for (int ni = 0; ni < 4; ni++) {
      int hw = hw0 + (pxq << 6) + ni * 16 + nif;
      #pragma unroll
      for (int r = 0; r < 4; r++) {
        int g = og * 128 + (ocq << 6) + mi * 16 + quad * 4 + r;
        float v = acc[mi][ni][r] + Bc[g];
        if (g < 18) {
          headom[(((size_t)b * 27 + g) << 14) + hw] = v;
        } else if (g < 27) {
          headom[(((size_t)b * 27 + g) << 14) + hw] = fast_sigmoid(v);
        } else if (g < 603) {
          headcol[(((size_t)b * 576 + (g - 27)) << 14) + hw] = f2bf(fast_tanh(v));
        }
      }
    }
  }
}

// ---- K5: sampler -> inp bf16 U[pix][k*64+c]; xt in bf16, 32 channels/thread -----------
__global__ __launch_bounds__(256, 4) void k_samp(
    const ushort* __restrict__ xtb, const float* __restrict__ headom,
    const ushort* __restrict__ headcol, ushort* __restrict__ U) {
  const int t = threadIdx.x;
  const int half32 = (t >> 6) & 1;            // channel half: c0 = half32*32
  const int pix = blockIdx.x * 128 + ((t >> 7) << 6) + (t & 63);
  const int b = pix >> 14, hw = pix & 16383;
  const int h = hw >> 7, w = hw & 127;
  const int c0 = half32 << 5;
  const float* hbom = headom + (((size_t)b * 27) << 14) + hw;
  const ushort* xb = xtb + ((size_t)b << 20);  // xtb[b][hw][64]
  const ushort* colb = headcol + (((size_t)b * 576) << 14) + hw;
  ushort* up = U + (size_t)pix * 576 + c0;

  #pragma unroll 1
  for (int k = 0; k < 9; k++) {
    float ox = hbom[(size_t)k << 14];
    float oy = hbom[(size_t)(9 + k) << 14];
    float mk = hbom[(size_t)(18 + k) << 14];
    float px = (float)(h + k / 3) + ox;
    float py = (float)(w + k % 3) + oy;
    float fx = floorf(px), fy = floorf(py);
    float qltx = fminf(fmaxf(fx, 0.f), 129.f);
    float qlty = fminf(fmaxf(fy, 0.f), 129.f);
    float qrbx = fminf(fmaxf(fx + 1.f, 0.f), 129.f);
    float qrby = fminf(fmaxf(fy + 1.f, 0.f), 129.f);
    float sx = fminf(fmaxf(px, 0.f), 129.f);
    float sy = fminf(fmaxf(py, 0.f), 129.f);
    float ax = 1.f + qltx - sx, bx = 1.f - qrbx + sx;
    float ay = 1.f + qlty - sy, by = 1.f - qrby + sy;
    int iltx = (int)qltx, ilty = (int)qlty, irbx = (int)qrbx, irby = (int)qrby;
    bool vltx = (iltx >= 1) && (iltx <= 128);
    bool vlty = (ilty >= 1) && (ilty <= 128);
    bool vrbx = (irbx >= 1) && (irbx <= 128);
    bool vrby = (irby >= 1) && (irby <= 128);
    float wl[4];
    int   ofs[4];
    wl[0] = (vltx && vlty) ? ax * ay : 0.f;
    wl[1] = (vrbx && vrby) ? bx * by : 0.f;
    wl[2] = (vltx && vrby) ? ax * by : 0.f;
    wl[3] = (vrbx && vlty) ? bx * ay : 0.f;
    ofs[0] = (vltx && vlty) ? ((iltx - 1) << 7) + (ilty - 1) : 0;
    ofs[1] = (vrbx && vrby) ? ((irbx - 1) << 7) + (irby - 1) : 0;
    ofs[2] = (vltx && vrby) ? ((iltx - 1) << 7) + (irby - 1) : 0;
    ofs[3] = (vrbx && vlty) ? ((irbx - 1) << 7) + (ilty - 1) : 0;

    float pos[32];
    #pragma unroll
    for (int j = 0; j < 32; j++) pos[j] = 0.f;
    #pragma unroll
    for (int corner = 0; corner < 4; corner++) {
      const ushort* p = xb + ((size_t)ofs[corner] << 6) + c0;
      float wgt = wl[corner];
      ushort tmp[32];
      #pragma unroll
      for (int q = 0; q < 4; q++)
        *(uint4*)(tmp + q * 8) = *(const uint4*)(p + q * 8);
      #pragma unroll
      for (int j = 0; j < 32; j++) pos[j] += wgt * bf2f(tmp[j]);
    }
    ushort vals[32];
    #pragma unroll
    for (int j = 0; j < 32; j++) {
      float col = bf2f(colb[(size_t)((c0 + j) * 9 + k) << 14]);
      vals[j] = f2bf((col + pos[j]) * mk);
    }
    #pragma unroll
    for (int q = 0; q < 4; q++)
      *(uint4*)(up + k * 64 + q * 8) = *(uint4*)(vals + q * 8);
  }
}

// ---- K6: MFMA GEMM out[64][pix] = W2 x U^T; packed-global af + double-buffered sP -----
__global__ __launch_bounds__(256) void k_out(
    const ushort* __restrict__ W2pk, const ushort* __restrict__ U,
    float* __restrict__ out) {
  __shared__ __align__(16) ushort sP[2 * 256 * 32];   // 32 KB
  const int t = threadIdx.x;
  const int lane = t & 63, wv = t >> 6;
  const int m0 = blockIdx.x * 256;
  const int bb = m0 >> 14, hw0 = m0 & 16383;
  const int srow = lane >> 2, sslot = lane & 3;
  const int nif = lane & 15, kb = lane >> 4;

  f32x4 acc[4][4];
  #pragma unroll
  for (int mi = 0; mi < 4; mi++)
    #pragma unroll
    for (int ni = 0; ni < 4; ni++) acc[mi][ni] = (f32x4){0.f, 0.f, 0.f, 0.f};

  #define STAGE(buf, ksv)                                                      \
    {                                                                          \
      _Pragma("unroll")                                                        \
      for (int c = 0; c < 4; c++) {                                            \
        int prow = (wv << 6) + (c << 4) + srow;                                \
        int g = (sslot - (prow >> 1)) & 3;                                     \
        gload_lds16(U + (size_t)(m0 + prow) * 576 + (ksv) * 32 + g * 8,        \
                    sP + ((buf) << 13) + (((wv << 6) + (c << 4)) << 5));       \
      }                                                                        \
    }

  STAGE(0, 0)
  for (int ks = 0; ks < 18; ks++) {
    __syncthreads();
    if (ks < 17) STAGE((ks + 1) & 1, ks + 1)
    const ushort* base = sP + ((ks & 1) << 13);
    s16x8 af[4], bfr[4];
    #pragma unroll
    for (int mi = 0; mi < 4; mi++)
      af[mi] = *(const s16x8*)(W2pk + ((((ks << 2) + mi) << 6) + lane) * 8);
    #pragma unroll
    for (int ni = 0; ni < 4; ni++) {
      int r = (wv << 6) + ni * 16 + nif;
      int s = (kb + (r >> 1)) & 3;
      bfr[ni] = *(const s16x8*)(base + r * 32 + s * 8);
    }
    #pragma unroll
    for (int mi = 0; mi < 4; mi++)
      #pragma unroll
      for (int ni = 0; ni < 4; ni++)
        acc[mi][ni] = __builtin_amdgcn_mfma_f32_16x16x32_bf16(af[mi], bfr[ni], acc[mi][ni], 0, 0, 0);
  }
  #undef STAGE

  const int quad = lane >> 4;
  #pragma unroll
  for (int mi = 0; mi < 4; mi++) {
    #pragma unroll
    for (int ni = 0; ni < 4; ni++) {
      int hw = hw0 + (wv << 6) + ni * 16 + nif;
      #pragma unroll
      for (int r = 0; r < 4; r++) {
        int g = mi * 16 + quad * 4 + r;
        out[(((size_t)bb * 64 + g) << 14) + hw] = acc[mi][ni][r];
      }
    }
  }
}

extern "C" void kernel_launch(void* const* d_in, const int* in_sizes, int n_in,
                              void* d_out, int out_size, void* d_ws, size_t ws_size,
                              hipStream_t stream) {
  const float* x     = (const float*)d_in[0];
  const float* ref   = (const float*)d_in[1];
  const float* wcd   = (const float*)d_in[2];
  const float* bcd   = (const float*)d_in[3];
  const float* wp    = (const float*)d_in[4];
  const float* bp    = (const float*)d_in[5];
  const float* wm    = (const float*)d_in[6];
  const float* bm    = (const float*)d_in[7];
  const float* wc    = (const float*)d_in[8];
  const float* bc    = (const float*)d_in[9];
  const float* wconv = (const float*)d_in[10];
  float* out = (float*)d_out;

  char* w8 = (char*)d_ws;
  ushort* Wpk     = (ushort*)(w8 + 0);           //    737,280 B
  float*  Bc      = (float*)(w8 + 737280);       //      2,560 B
  ushort* W2pk    = (ushort*)(w8 + 739840);      //     73,728 B
  ushort* fusedt  = (ushort*)(w8 + 813568);      //  8,388,608 B (pixel-major)
  ushort* U       = (ushort*)(w8 + 9202176);     // 75,497,472 B
  float*  headom  = (float*)(w8 + 84699648);     //  7,077,888 B
  ushort* headcol = (ushort*)(w8 + 91777536);    // 75,497,472 B
  ushort* xtb     = (ushort*)(w8 + 167275008);   //  8,388,608 B -> total 175,663,616 B

  k_merge <<<1440, 256, 0, stream>>>(wp, bp, wm, bm, wc, bc, wconv, Wpk, Bc, W2pk);
  k_fused <<<256, 256, 0, stream>>>(x, ref, wcd, bcd, fusedt);
  k_xt    <<<1024, 256, 0, stream>>>(x, xtb);
  k_gemm  <<<dim3(5, 512), 256, 0, stream>>>(Wpk, fusedt, Bc, headom, headcol);
  k_samp  <<<512, 256, 0, stream>>>(xtb, headom, headcol, U);
  k_out   <<<256, 256, 0, stream>>>(W2pk, U, out);
}

// Round 9
// 295.340 us; speedup vs baseline: 1.5368x; 1.3254x over previous
//
#include <hip/hip_runtime.h>
#include <math.h>

typedef short s16x8 __attribute__((ext_vector_type(8)));
typedef float f32x4 __attribute__((ext_vector_type(4)));

__device__ inline ushort f2bf(float f) {
  unsigned u = __float_as_uint(f);
  u = (u + 0x7FFF + ((u >> 16) & 1)) >> 16;
  return (ushort)u;
}
__device__ inline float bf2f(ushort u) {
  return __uint_as_float(((unsigned)u) << 16);
}
__device__ inline void gload_lds16(const void* g, void* l) {
  __builtin_amdgcn_global_load_lds(
      (const __attribute__((address_space(1))) unsigned*)g,
      (__attribute__((address_space(3))) unsigned*)l, 16, 0, 0);
}
// fast activations: v_exp_f32 + v_rcp_f32; saturate correctly at +/-inf.
__device__ inline float fast_tanh(float v) {
  float e = __builtin_amdgcn_exp2f(v * 2.8853900817779268f);   // exp(2v)
  return 1.f - 2.f * __builtin_amdgcn_rcpf(e + 1.f);
}
__device__ inline float fast_sigmoid(float v) {
  float e = __builtin_amdgcn_exp2f(v * -1.4426950408889634f);  // exp(-v)
  return __builtin_amdgcn_rcpf(1.f + e);
}

// ---- K0: pack weights into MFMA-fragment order ----------------------------------------
// Wpk[og 5][ks 18][ocq 2][mi 4][lane 64][e 8]: af[mi] for (og,ks,ocq,lane) contiguous.
//   g = og*128+ocq*64+mi*16+(lane&15); ci = (ks&1)*32+(lane>>4)*8+e; kk = ks>>1.
// W2pk[ks 18][mi 4][lane 64][e 8]: o = mi*16+(lane&15); p = ks*32+(lane>>4)*8+e;
//   kk = p>>6, c = p&63 (k-major permuted axis), orig col = c*9+kk.
__global__ __launch_bounds__(256) void k_merge(
    const float* __restrict__ wp, const float* __restrict__ bp,
    const float* __restrict__ wm, const float* __restrict__ bm,
    const float* __restrict__ wc, const float* __restrict__ bc,
    const float* __restrict__ wconv,
    ushort* __restrict__ Wpk, float* __restrict__ Bc, ushort* __restrict__ W2pk) {
  int i = blockIdx.x * 256 + threadIdx.x;
  if (i < 368640) {
    int e = i & 7, lane = (i >> 3) & 63, mi = (i >> 9) & 3, ocq = (i >> 11) & 1;
    int hi = i >> 12;                 // 0..89
    int ks = hi % 18, og = hi / 18;
    int g = og * 128 + ocq * 64 + mi * 16 + (lane & 15);
    int ci = ((ks & 1) << 5) + ((lane >> 4) << 3) + e;
    int kk = ks >> 1;
    int col = ci * 9 + kk;
    float v = 0.f;
    if (g < 18)       v = wp[g * 576 + col];
    else if (g < 27)  v = wm[(g - 18) * 576 + col];
    else if (g < 603) v = wc[(g - 27) * 576 + col];
    Wpk[i] = f2bf(v);
  }
  if (i < 36864) {
    int e = i & 7, lane = (i >> 3) & 63, mi = (i >> 9) & 3, ks = i >> 11;  // 0..17
    int o = mi * 16 + (lane & 15);
    int p = (ks << 5) + ((lane >> 4) << 3) + e;
    int kk2 = p >> 6, c = p & 63;
    W2pk[i] = f2bf(wconv[o * 576 + c * 9 + kk2]);
  }
  if (i < 640)
    Bc[i] = (i < 18) ? bp[i] : (i < 27) ? bm[i - 18] : (i < 603) ? bc[i - 27] : 0.f;
}

// ---- K1: fused = 1x1 conv over concat(x, ref) -> PIXEL-MAJOR bf16 fusedt[pix][64] -----
__global__ __launch_bounds__(256) void k_fused(
    const float* __restrict__ x, const float* __restrict__ ref,
    const float* __restrict__ wcd, const float* __restrict__ bcd,
    ushort* __restrict__ fusedt) {
  __shared__ float sw[128 * 64];
  __shared__ float sb[64];
  for (int i = threadIdx.x; i < 128 * 64; i += 256) {
    int ci = i >> 6, o = i & 63;
    sw[i] = wcd[o * 128 + ci];
  }
  if (threadIdx.x < 64) sb[threadIdx.x] = bcd[threadIdx.x];
  __syncthreads();

  int pix = blockIdx.x * 256 + threadIdx.x;
  int b = pix >> 14, hw = pix & 16383;
  const float* xb = x   + ((size_t)b * 64 << 14) + hw;
  const float* rb = ref + ((size_t)b * 64 << 14) + hw;

  float4 acc[16];
  #pragma unroll
  for (int o4 = 0; o4 < 16; o4++)
    acc[o4] = make_float4(sb[4*o4], sb[4*o4+1], sb[4*o4+2], sb[4*o4+3]);

  for (int ci = 0; ci < 64; ci++) {
    float v = xb[(size_t)ci << 14];
    const float4* wr = (const float4*)&sw[ci * 64];
    #pragma unroll
    for (int o4 = 0; o4 < 16; o4++) {
      float4 w4 = wr[o4];
      acc[o4].x += w4.x * v; acc[o4].y += w4.y * v;
      acc[o4].z += w4.z * v; acc[o4].w += w4.w * v;
    }
  }
  for (int ci = 0; ci < 64; ci++) {
    float v = rb[(size_t)ci << 14];
    const float4* wr = (const float4*)&sw[(64 + ci) * 64];
    #pragma unroll
    for (int o4 = 0; o4 < 16; o4++) {
      float4 w4 = wr[o4];
      acc[o4].x += w4.x * v; acc[o4].y += w4.y * v;
      acc[o4].z += w4.z * v; acc[o4].w += w4.w * v;
    }
  }
  ushort vals[64];
  #pragma unroll
  for (int o4 = 0; o4 < 16; o4++) {
    vals[4*o4+0] = f2bf(acc[o4].x); vals[4*o4+1] = f2bf(acc[o4].y);
    vals[4*o4+2] = f2bf(acc[o4].z); vals[4*o4+3] = f2bf(acc[o4].w);
  }
  ushort* fb = fusedt + ((size_t)pix << 6);
  #pragma unroll
  for (int q = 0; q < 8; q++)
    *(uint4*)(fb + q * 8) = *(uint4*)(vals + q * 8);
}

// ---- K2: xtb[b][hw][c] bf16 pixel-major transpose of x -------------------------------
__global__ __launch_bounds__(256) void k_xt(
    const float* __restrict__ x, ushort* __restrict__ xtb) {
  __shared__ float sx[64][65];
  const int t = threadIdx.x;
  const int b = blockIdx.x >> 8, hw0 = (blockIdx.x & 255) << 6;
  for (int i = t; i < 4096; i += 256) {
    int c = i >> 6, hwi = i & 63;
    sx[c][hwi] = x[((size_t)(b * 64 + c) << 14) + hw0 + hwi];
  }
  __syncthreads();
  for (int i = t; i < 4096; i += 256) {
    int hwi = i >> 6, c = i & 63;
    xtb[(((size_t)b << 14) + hw0 + hwi) * 64 + c] = f2bf(sx[c][hwi]);
  }
}

// ---- K3: DIRECT-CONV MFMA GEMM head = W(*)fused; og-loop inside block -----------------
// grid (rowid 512); block = 4 waves; per og: tile 128oc x 128px. sF staged ONCE.
__global__ __launch_bounds__(256) void k_gemm(
    const ushort* __restrict__ Wpk, const ushort* __restrict__ fusedt,
    const float* __restrict__ Bc,
    float* __restrict__ headom, ushort* __restrict__ headcol) {
  __shared__ __align__(16) ushort sF[3 * 130 * 64];   // 49,920 B
  const int t = threadIdx.x;
  const int lane = t & 63, wv = t >> 6;
  const int rowid = blockIdx.x;           // b*128 + h
  const int b = rowid >> 7, h = rowid & 127;
  const int hw0 = (rowid << 7) & 16383;

  // stage fused rows h-1..h+1, w1 in [0,130) covering gw in [-1,128]
  for (int idx = t; idx < 3120; idx += 256) {     // 390 pixels x 8 ci-chunks
    int p = idx >> 3, j = idx & 7;
    int row = p / 130, w1 = p - row * 130;
    int gh = h + row - 1, gw = w1 - 1;
    uint4 v = make_uint4(0u, 0u, 0u, 0u);
    if (gh >= 0 && gh < 128 && (unsigned)gw < 128u)
      v = *(const uint4*)(fusedt + ((size_t)((b << 14) + (gh << 7) + gw) << 6) + j * 8);
    int slot = (j + w1) & 7;
    *(uint4*)(sF + (p << 6) + slot * 8) = v;
  }
  __syncthreads();

  const int ocq = wv & 1, pxq = wv >> 1;
  const int nif = lane & 15, kb = lane >> 4;
  const int quad = lane >> 4;

  #pragma unroll 1
  for (int og = 0; og < 5; og++) {
    f32x4 acc[4][4];
    #pragma unroll
    for (int mi = 0; mi < 4; mi++)
      #pragma unroll
      for (int ni = 0; ni < 4; ni++) acc[mi][ni] = (f32x4){0.f, 0.f, 0.f, 0.f};

    #pragma unroll 2
    for (int ks = 0; ks < 18; ks++) {
      const int kk = ks >> 1, half = ks & 1;
      const int dr = kk / 3, dc = kk - dr * 3;
      const ushort* wp8 = Wpk + ((size_t)((((og * 18 + ks) << 1) + ocq) << 11)) + (lane << 3);
      s16x8 af[4], bfr[4];
      #pragma unroll
      for (int mi = 0; mi < 4; mi++)
        af[mi] = *(const s16x8*)(wp8 + (mi << 9));
      const int gci = half * 4 + kb;        // logical ci-group 0..7
      #pragma unroll
      for (int ni = 0; ni < 4; ni++) {
        int r = (pxq << 6) + ni * 16 + nif;
        int w1 = r + dc;
        int slot = (gci + w1) & 7;
        bfr[ni] = *(const s16x8*)(sF + ((dr * 130 + w1) << 6) + slot * 8);
      }
      #pragma unroll
      for (int mi = 0; mi < 4; mi++)
        #pragma unroll
        for (int ni = 0; ni < 4; ni++)
          acc[mi][ni] = __builtin_amdgcn_mfma_f32_16x16x32_bf16(af[mi], bfr[ni], acc[mi][ni], 0, 0, 0);
    }

    #pragma unroll
    for (int mi = 0; mi < 4; mi++) {
      #pragma unroll
      for (int ni = 0; ni < 4; ni++) {
        int hw = hw0 + (pxq << 6) + ni * 16 + nif;
        #pragma unroll
        for (int r = 0; r < 4; r++) {
          int g = og * 128 + (ocq << 6) + mi * 16 + quad * 4 + r;
          float v = acc[mi][ni][r] + Bc[g];
          if (g < 18) {
            headom[(((size_t)b * 27 + g) << 14) + hw] = v;
          } else if (g < 27) {
            headom[(((size_t)b * 27 + g) << 14) + hw] = fast_sigmoid(v);
          } else if (g < 603) {
            headcol[(((size_t)b * 576 + (g - 27)) << 14) + hw] = f2bf(fast_tanh(v));
          }
        }
      }
    }
  }
}

// ---- K4: FUSED sampler + final GEMM: out[64][pix] = W2 x inp^T, inp never hits HBM ----
// grid 512; block 256 = 4 waves; 128 px/block. Per k (9): sample 128px x 64ch into
// LDS (dbuf, slot-rotated), then each wave MFMAs 2 ks-steps. acc[mi 2][ni 4].
// Sampling role: thread = (chalf = t>>7 -> 32 ch, pxl = t&127).
// MFMA role: wave wv: pxq = wv&1 (64 px), ocq = wv>>1 (32 oc).
__global__ __launch_bounds__(256) void k_sampout(
    const ushort* __restrict__ xtb, const float* __restrict__ headom,
    const ushort* __restrict__ headcol, const ushort* __restrict__ W2pk,
    float* __restrict__ out) {
  __shared__ __align__(16) ushort sU[2][128 * 64];   // 32 KB
  const int t = threadIdx.x;
  const int lane = t & 63, wv = t >> 6;
  const int m0 = blockIdx.x * 128;
  const int b = m0 >> 14, hw0 = m0 & 16383;

  const int chalf = t >> 7, pxl = t & 127;
  const int c0 = chalf << 5;
  const int hw = hw0 + pxl;
  const int h = hw >> 7, w = hw & 127;
  const float* hbom = headom + (((size_t)b * 27) << 14) + hw;
  const ushort* xb = xtb + ((size_t)b << 20);
  const ushort* colb = headcol + (((size_t)b * 576) << 14) + hw;

  const int pxq = wv & 1, ocq = wv >> 1;
  const int nif = lane & 15, kb = lane >> 4;

  f32x4 acc[2][4];
  #pragma unroll
  for (int mi = 0; mi < 2; mi++)
    #pragma unroll
    for (int ni = 0; ni < 4; ni++) acc[mi][ni] = (f32x4){0.f, 0.f, 0.f, 0.f};

  #pragma unroll 1
  for (int k = 0; k < 9; k++) {
    // ---- sample 32 channels of pixel pxl ----
    float ox = hbom[(size_t)k << 14];
    float oy = hbom[(size_t)(9 + k) << 14];
    float mk = hbom[(size_t)(18 + k) << 14];
    float px = (float)(h + k / 3) + ox;
    float py = (float)(w + k % 3) + oy;
    float fx = floorf(px), fy = floorf(py);
    float qltx = fminf(fmaxf(fx, 0.f), 129.f);
    float qlty = fminf(fmaxf(fy, 0.f), 129.f);
    float qrbx = fminf(fmaxf(fx + 1.f, 0.f), 129.f);
    float qrby = fminf(fmaxf(fy + 1.f, 0.f), 129.f);
    float sx = fminf(fmaxf(px, 0.f), 129.f);
    float sy = fminf(fmaxf(py, 0.f), 129.f);
    float ax = 1.f + qltx - sx, bx = 1.f - qrbx + sx;
    float ay = 1.f + qlty - sy, by = 1.f - qrby + sy;
    int iltx = (int)qltx, ilty = (int)qlty, irbx = (int)qrbx, irby = (int)qrby;
    bool vltx = (iltx >= 1) && (iltx <= 128);
    bool vlty = (ilty >= 1) && (ilty <= 128);
    bool vrbx = (irbx >= 1) && (irbx <= 128);
    bool vrby = (irby >= 1) && (irby <= 128);
    float wl[4];
    int   ofs[4];
    wl[0] = (vltx && vlty) ? ax * ay : 0.f;
    wl[1] = (vrbx && vrby) ? bx * by : 0.f;
    wl[2] = (vltx && vrby) ? ax * by : 0.f;
    wl[3] = (vrbx && vlty) ? bx * ay : 0.f;
    ofs[0] = (vltx && vlty) ? ((iltx - 1) << 7) + (ilty - 1) : 0;
    ofs[1] = (vrbx && vrby) ? ((irbx - 1) << 7) + (irby - 1) : 0;
    ofs[2] = (vltx && vrby) ? ((iltx - 1) << 7) + (irby - 1) : 0;
    ofs[3] = (vrbx && vlty) ? ((irbx - 1) << 7) + (ilty - 1) : 0;

    float pos[32];
    #pragma unroll
    for (int j = 0; j < 32; j++) pos[j] = 0.f;
    #pragma unroll
    for (int corner = 0; corner < 4; corner++) {
      const ushort* p = xb + ((size_t)ofs[corner] << 6) + c0;
      float wgt = wl[corner];
      ushort tmp[32];
      #pragma unroll
      for (int q = 0; q < 4; q++)
        *(uint4*)(tmp + q * 8) = *(const uint4*)(p + q * 8);
      #pragma unroll
      for (int j = 0; j < 32; j++) pos[j] += wgt * bf2f(tmp[j]);
    }
    ushort vals[32];
    #pragma unroll
    for (int j = 0; j < 32; j++) {
      float col = bf2f(colb[(size_t)((c0 + j) * 9 + k) << 14]);
      vals[j] = f2bf((col + pos[j]) * mk);
    }
    // write to LDS buffer k&1 with 8-slot rotation by pixel row
    ushort* su = &sU[k & 1][pxl << 6];
    #pragma unroll
    for (int q = 0; q < 4; q++) {
      int slot = ((chalf << 2) + q + pxl) & 7;
      *(uint4*)(su + slot * 8) = *(uint4*)(vals + q * 8);
    }
    __syncthreads();

    // ---- MFMA: 2 ks-steps over this k-tile ----
    const ushort* base = &sU[k & 1][0];
    #pragma unroll
    for (int khalf = 0; khalf < 2; khalf++) {
      int ks = (k << 1) + khalf;
      s16x8 af[2], bfr[4];
      #pragma unroll
      for (int mi = 0; mi < 2; mi++)
        af[mi] = *(const s16x8*)(W2pk + ((((ks << 2) + (ocq << 1) + mi) << 6) + lane) * 8);
      const int g0 = (khalf << 2) + kb;
      #pragma unroll
      for (int ni = 0; ni < 4; ni++) {
        int r = (pxq << 6) + ni * 16 + nif;
        int slot = (g0 + r) & 7;
        bfr[ni] = *(const s16x8*)(base + (r << 6) + slot * 8);
      }
      #pragma unroll
      for (int mi = 0; mi < 2; mi++)
        #pragma unroll
        for (int ni = 0; ni < 4; ni++)
          acc[mi][ni] = __builtin_amdgcn_mfma_f32_16x16x32_bf16(af[mi], bfr[ni], acc[mi][ni], 0, 0, 0);
    }
  }

  const int quad = lane >> 4;
  #pragma unroll
  for (int mi = 0; mi < 2; mi++) {
    #pragma unroll
    for (int ni = 0; ni < 4; ni++) {
      int hwp = hw0 + (pxq << 6) + ni * 16 + nif;
      #pragma unroll
      for (int r = 0; r < 4; r++) {
        int o = (ocq << 5) + mi * 16 + quad * 4 + r;
        out[(((size_t)b * 64 + o) << 14) + hwp] = acc[mi][ni][r];
      }
    }
  }
}

extern "C" void kernel_launch(void* const* d_in, const int* in_sizes, int n_in,
                              void* d_out, int out_size, void* d_ws, size_t ws_size,
                              hipStream_t stream) {
  const float* x     = (const float*)d_in[0];
  const float* ref   = (const float*)d_in[1];
  const float* wcd   = (const float*)d_in[2];
  const float* bcd   = (const float*)d_in[3];
  const float* wp    = (const float*)d_in[4];
  const float* bp    = (const float*)d_in[5];
  const float* wm    = (const float*)d_in[6];
  const float* bm    = (const float*)d_in[7];
  const float* wc    = (const float*)d_in[8];
  const float* bc    = (const float*)d_in[9];
  const float* wconv = (const float*)d_in[10];
  float* out = (float*)d_out;

  char* w8 = (char*)d_ws;
  ushort* Wpk     = (ushort*)(w8 + 0);           //    737,280 B
  float*  Bc      = (float*)(w8 + 737280);       //      2,560 B
  ushort* W2pk    = (ushort*)(w8 + 739840);      //     73,728 B
  ushort* fusedt  = (ushort*)(w8 + 813568);      //  8,388,608 B (pixel-major)
  float*  headom  = (float*)(w8 + 9202176);      //  7,077,888 B
  ushort* headcol = (ushort*)(w8 + 16280064);    // 75,497,472 B
  ushort* xtb     = (ushort*)(w8 + 91777536);    //  8,388,608 B -> total 100,166,144 B

  k_merge  <<<1440, 256, 0, stream>>>(wp, bp, wm, bm, wc, bc, wconv, Wpk, Bc, W2pk);
  k_fused  <<<256, 256, 0, stream>>>(x, ref, wcd, bcd, fusedt);
  k_xt     <<<1024, 256, 0, stream>>>(x, xtb);
  k_gemm   <<<512, 256, 0, stream>>>(Wpk, fusedt, Bc, headom, headcol);
  k_sampout<<<512, 256, 0, stream>>>(xtb, headom, headcol, W2pk, out);
}

// Round 10
// 279.574 us; speedup vs baseline: 1.6235x; 1.0564x over previous
//
#include <hip/hip_runtime.h>
#include <math.h>

typedef short s16x8 __attribute__((ext_vector_type(8)));
typedef float f32x4 __attribute__((ext_vector_type(4)));

__device__ inline ushort f2bf(float f) {
  unsigned u = __float_as_uint(f);
  u = (u + 0x7FFF + ((u >> 16) & 1)) >> 16;
  return (ushort)u;
}
__device__ inline float bf2f(ushort u) {
  return __uint_as_float(((unsigned)u) << 16);
}
__device__ inline void gload_lds16(const void* g, void* l) {
  __builtin_amdgcn_global_load_lds(
      (const __attribute__((address_space(1))) unsigned*)g,
      (__attribute__((address_space(3))) unsigned*)l, 16, 0, 0);
}
// fast activations: v_exp_f32 + v_rcp_f32; saturate correctly at +/-inf.
__device__ inline float fast_tanh(float v) {
  float e = __builtin_amdgcn_exp2f(v * 2.8853900817779268f);   // exp(2v)
  return 1.f - 2.f * __builtin_amdgcn_rcpf(e + 1.f);
}
__device__ inline float fast_sigmoid(float v) {
  float e = __builtin_amdgcn_exp2f(v * -1.4426950408889634f);  // exp(-v)
  return __builtin_amdgcn_rcpf(1.f + e);
}

// ---- PERMUTED head-row space (640 rows):
//   g in [0,18)   : off (linear, fp32 -> headom)
//   g in [18,27)  : mod (sigmoid, fp32 -> headom)
//   g in [27,64)  : zero pad (no store)
//   g in [64,640) : col, j = g-64 = k*64 + c  (tanh, bf16 -> headcol[pix][576])
//     source col channel cc = c*9 + k  (c = j&63, k = j>>6)
// ---- K0: pack weights into MFMA-fragment order in permuted row space ------------------
// Wpk[og 5][ks 18][ocq 2][mi 4][lane 64][e 8]; W2pk[ks 18][mi 4][lane 64][e 8] unchanged.
__global__ __launch_bounds__(256) void k_merge(
    const float* __restrict__ wp, const float* __restrict__ bp,
    const float* __restrict__ wm, const float* __restrict__ bm,
    const float* __restrict__ wc, const float* __restrict__ bc,
    const float* __restrict__ wconv,
    ushort* __restrict__ Wpk, float* __restrict__ Bc, ushort* __restrict__ W2pk) {
  int i = blockIdx.x * 256 + threadIdx.x;
  if (i < 368640) {
    int e = i & 7, lane = (i >> 3) & 63, mi = (i >> 9) & 3, ocq = (i >> 11) & 1;
    int hi = i >> 12;                 // 0..89
    int ks = hi % 18, og = hi / 18;
    int g = og * 128 + ocq * 64 + mi * 16 + (lane & 15);
    int ci = ((ks & 1) << 5) + ((lane >> 4) << 3) + e;
    int kk = ks >> 1;
    int col = ci * 9 + kk;
    float v = 0.f;
    if (g < 18)       v = wp[g * 576 + col];
    else if (g < 27)  v = wm[(g - 18) * 576 + col];
    else if (g >= 64) {
      int j = g - 64;
      int cc = (j & 63) * 9 + (j >> 6);
      v = wc[cc * 576 + col];
    }
    Wpk[i] = f2bf(v);
  }
  if (i < 36864) {
    int e = i & 7, lane = (i >> 3) & 63, mi = (i >> 9) & 3, ks = i >> 11;  // 0..17
    int o = mi * 16 + (lane & 15);
    int p = (ks << 5) + ((lane >> 4) << 3) + e;
    int kk2 = p >> 6, c = p & 63;
    W2pk[i] = f2bf(wconv[o * 576 + c * 9 + kk2]);
  }
  if (i < 640) {
    float bv = 0.f;
    if (i < 18)       bv = bp[i];
    else if (i < 27)  bv = bm[i - 18];
    else if (i >= 64) {
      int j = i - 64;
      bv = bc[(j & 63) * 9 + (j >> 6)];
    }
    Bc[i] = bv;
  }
}

// ---- K1: fused = 1x1 conv over concat(x, ref) -> PIXEL-MAJOR bf16 fusedt[pix][64] -----
__global__ __launch_bounds__(256) void k_fused(
    const float* __restrict__ x, const float* __restrict__ ref,
    const float* __restrict__ wcd, const float* __restrict__ bcd,
    ushort* __restrict__ fusedt) {
  __shared__ float sw[128 * 64];
  __shared__ float sb[64];
  for (int i = threadIdx.x; i < 128 * 64; i += 256) {
    int ci = i >> 6, o = i & 63;
    sw[i] = wcd[o * 128 + ci];
  }
  if (threadIdx.x < 64) sb[threadIdx.x] = bcd[threadIdx.x];
  __syncthreads();

  int pix = blockIdx.x * 256 + threadIdx.x;
  int b = pix >> 14, hw = pix & 16383;
  const float* xb = x   + ((size_t)b * 64 << 14) + hw;
  const float* rb = ref + ((size_t)b * 64 << 14) + hw;

  float4 acc[16];
  #pragma unroll
  for (int o4 = 0; o4 < 16; o4++)
    acc[o4] = make_float4(sb[4*o4], sb[4*o4+1], sb[4*o4+2], sb[4*o4+3]);

  for (int ci = 0; ci < 64; ci++) {
    float v = xb[(size_t)ci << 14];
    const float4* wr = (const float4*)&sw[ci * 64];
    #pragma unroll
    for (int o4 = 0; o4 < 16; o4++) {
      float4 w4 = wr[o4];
      acc[o4].x += w4.x * v; acc[o4].y += w4.y * v;
      acc[o4].z += w4.z * v; acc[o4].w += w4.w * v;
    }
  }
  for (int ci = 0; ci < 64; ci++) {
    float v = rb[(size_t)ci << 14];
    const float4* wr = (const float4*)&sw[(64 + ci) * 64];
    #pragma unroll
    for (int o4 = 0; o4 < 16; o4++) {
      float4 w4 = wr[o4];
      acc[o4].x += w4.x * v; acc[o4].y += w4.y * v;
      acc[o4].z += w4.z * v; acc[o4].w += w4.w * v;
    }
  }
  ushort vals[64];
  #pragma unroll
  for (int o4 = 0; o4 < 16; o4++) {
    vals[4*o4+0] = f2bf(acc[o4].x); vals[4*o4+1] = f2bf(acc[o4].y);
    vals[4*o4+2] = f2bf(acc[o4].z); vals[4*o4+3] = f2bf(acc[o4].w);
  }
  ushort* fb = fusedt + ((size_t)pix << 6);
  #pragma unroll
  for (int q = 0; q < 8; q++)
    *(uint4*)(fb + q * 8) = *(uint4*)(vals + q * 8);
}

// ---- K2: xtb[b][hw][c] bf16 pixel-major transpose of x -------------------------------
__global__ __launch_bounds__(256) void k_xt(
    const float* __restrict__ x, ushort* __restrict__ xtb) {
  __shared__ float sx[64][65];
  const int t = threadIdx.x;
  const int b = blockIdx.x >> 8, hw0 = (blockIdx.x & 255) << 6;
  for (int i = t; i < 4096; i += 256) {
    int c = i >> 6, hwi = i & 63;
    sx[c][hwi] = x[((size_t)(b * 64 + c) << 14) + hw0 + hwi];
  }
  __syncthreads();
  for (int i = t; i < 4096; i += 256) {
    int hwi = i >> 6, c = i & 63;
    xtb[(((size_t)b << 14) + hw0 + hwi) * 64 + c] = f2bf(sx[c][hwi]);
  }
}

// ---- K3: DIRECT-CONV MFMA GEMM head = W(*)fused; og-loop inside block -----------------
// grid (rowid 512); block = 4 waves; per og: tile 128oc x 128px. sF staged ONCE.
// Epilogue: col rows -> packed 8B bf16 stores into pixel-major headcol[pix][576].
__global__ __launch_bounds__(256) void k_gemm(
    const ushort* __restrict__ Wpk, const ushort* __restrict__ fusedt,
    const float* __restrict__ Bc,
    float* __restrict__ headom, ushort* __restrict__ headcol) {
  __shared__ __align__(16) ushort sF[3 * 130 * 64];   // 49,920 B
  const int t = threadIdx.x;
  const int lane = t & 63, wv = t >> 6;
  const int rowid = blockIdx.x;           // b*128 + h
  const int b = rowid >> 7, h = rowid & 127;
  const int hw0 = (rowid << 7) & 16383;

  // stage fused rows h-1..h+1, w1 in [0,130) covering gw in [-1,128]
  for (int idx = t; idx < 3120; idx += 256) {     // 390 pixels x 8 ci-chunks
    int p = idx >> 3, j = idx & 7;
    int row = p / 130, w1 = p - row * 130;
    int gh = h + row - 1, gw = w1 - 1;
    uint4 v = make_uint4(0u, 0u, 0u, 0u);
    if (gh >= 0 && gh < 128 && (unsigned)gw < 128u)
      v = *(const uint4*)(fusedt + ((size_t)((b << 14) + (gh << 7) + gw) << 6) + j * 8);
    int slot = (j + w1) & 7;
    *(uint4*)(sF + (p << 6) + slot * 8) = v;
  }
  __syncthreads();

  const int ocq = wv & 1, pxq = wv >> 1;
  const int nif = lane & 15, kb = lane >> 4;
  const int quad = lane >> 4;

  #pragma unroll 1
  for (int og = 0; og < 5; og++) {
    f32x4 acc[4][4];
    #pragma unroll
    for (int mi = 0; mi < 4; mi++)
      #pragma unroll
      for (int ni = 0; ni < 4; ni++) acc[mi][ni] = (f32x4){0.f, 0.f, 0.f, 0.f};

    #pragma unroll 2
    for (int ks = 0; ks < 18; ks++) {
      const int kk = ks >> 1, half = ks & 1;
      const int dr = kk / 3, dc = kk - dr * 3;
      const ushort* wp8 = Wpk + ((size_t)((((og * 18 + ks) << 1) + ocq) << 11)) + (lane << 3);
      s16x8 af[4], bfr[4];
      #pragma unroll
      for (int mi = 0; mi < 4; mi++)
        af[mi] = *(const s16x8*)(wp8 + (mi << 9));
      const int gci = half * 4 + kb;        // logical ci-group 0..7
      #pragma unroll
      for (int ni = 0; ni < 4; ni++) {
        int r = (pxq << 6) + ni * 16 + nif;
        int w1 = r + dc;
        int slot = (gci + w1) & 7;
        bfr[ni] = *(const s16x8*)(sF + ((dr * 130 + w1) << 6) + slot * 8);
      }
      #pragma unroll
      for (int mi = 0; mi < 4; mi++)
        #pragma unroll
        for (int ni = 0; ni < 4; ni++)
          acc[mi][ni] = __builtin_amdgcn_mfma_f32_16x16x32_bf16(af[mi], bfr[ni], acc[mi][ni], 0, 0, 0);
    }

    #pragma unroll
    for (int mi = 0; mi < 4; mi++) {
      const int gb = og * 128 + (ocq << 6) + mi * 16 + (quad << 2);
      #pragma unroll
      for (int ni = 0; ni < 4; ni++) {
        int hw = hw0 + (pxq << 6) + ni * 16 + nif;
        if (gb >= 64) {               // col fast path (uniform per quad here)
          float4 b4 = *(const float4*)(Bc + gb);
          ushort v4[4];
          v4[0] = f2bf(fast_tanh(acc[mi][ni][0] + b4.x));
          v4[1] = f2bf(fast_tanh(acc[mi][ni][1] + b4.y));
          v4[2] = f2bf(fast_tanh(acc[mi][ni][2] + b4.z));
          v4[3] = f2bf(fast_tanh(acc[mi][ni][3] + b4.w));
          *(uint2*)(headcol + ((size_t)((b << 14) + hw)) * 576 + (gb - 64)) = *(uint2*)v4;
        } else {
          #pragma unroll
          for (int r = 0; r < 4; r++) {
            int g = gb + r;
            float v = acc[mi][ni][r] + Bc[g];
            if (g < 18)       headom[(((size_t)b * 27 + g) << 14) + hw] = v;
            else if (g < 27)  headom[(((size_t)b * 27 + g) << 14) + hw] = fast_sigmoid(v);
            // 27..63: zero-pad rows, no store
          }
        }
      }
    }
  }
}

// ---- K4: FUSED sampler + final GEMM: out[64][pix] = W2 x inp^T ------------------------
// grid 512; block 256 = 4 waves; 128 px/block. Per k (9): sample 128px x 64ch into
// LDS (dbuf, slot-rotated), then each wave MFMAs 2 ks-steps. acc[mi 2][ni 4].
__global__ __launch_bounds__(256) void k_sampout(
    const ushort* __restrict__ xtb, const float* __restrict__ headom,
    const ushort* __restrict__ headcol, const ushort* __restrict__ W2pk,
    float* __restrict__ out) {
  __shared__ __align__(16) ushort sU[2][128 * 64];   // 32 KB
  const int t = threadIdx.x;
  const int lane = t & 63, wv = t >> 6;
  const int m0 = blockIdx.x * 128;
  const int b = m0 >> 14, hw0 = m0 & 16383;

  const int chalf = t >> 7, pxl = t & 127;
  const int c0 = chalf << 5;
  const int hw = hw0 + pxl;
  const int h = hw >> 7, w = hw & 127;
  const float* hbom = headom + (((size_t)b * 27) << 14) + hw;
  const ushort* xb = xtb + ((size_t)b << 20);
  const ushort* colp = headcol + (size_t)((b << 14) + hw) * 576;

  const int pxq = wv & 1, ocq = wv >> 1;
  const int nif = lane & 15, kb = lane >> 4;

  f32x4 acc[2][4];
  #pragma unroll
  for (int mi = 0; mi < 2; mi++)
    #pragma unroll
    for (int ni = 0; ni < 4; ni++) acc[mi][ni] = (f32x4){0.f, 0.f, 0.f, 0.f};

  #pragma unroll 1
  for (int k = 0; k < 9; k++) {
    // ---- sample 32 channels of pixel pxl ----
    float ox = hbom[(size_t)k << 14];
    float oy = hbom[(size_t)(9 + k) << 14];
    float mk = hbom[(size_t)(18 + k) << 14];
    float px = (float)(h + k / 3) + ox;
    float py = (float)(w + k % 3) + oy;
    float fx = floorf(px), fy = floorf(py);
    float qltx = fminf(fmaxf(fx, 0.f), 129.f);
    float qlty = fminf(fmaxf(fy, 0.f), 129.f);
    float qrbx = fminf(fmaxf(fx + 1.f, 0.f), 129.f);
    float qrby = fminf(fmaxf(fy + 1.f, 0.f), 129.f);
    float sx = fminf(fmaxf(px, 0.f), 129.f);
    float sy = fminf(fmaxf(py, 0.f), 129.f);
    float ax = 1.f + qltx - sx, bx = 1.f - qrbx + sx;
    float ay = 1.f + qlty - sy, by = 1.f - qrby + sy;
    int iltx = (int)qltx, ilty = (int)qlty, irbx = (int)qrbx, irby = (int)qrby;
    bool vltx = (iltx >= 1) && (iltx <= 128);
    bool vlty = (ilty >= 1) && (ilty <= 128);
    bool vrbx = (irbx >= 1) && (irbx <= 128);
    bool vrby = (irby >= 1) && (irby <= 128);
    float wl[4];
    int   ofs[4];
    wl[0] = (vltx && vlty) ? ax * ay : 0.f;
    wl[1] = (vrbx && vrby) ? bx * by : 0.f;
    wl[2] = (vltx && vrby) ? ax * by : 0.f;
    wl[3] = (vrbx && vlty) ? bx * ay : 0.f;
    ofs[0] = (vltx && vlty) ? ((iltx - 1) << 7) + (ilty - 1) : 0;
    ofs[1] = (vrbx && vrby) ? ((irbx - 1) << 7) + (irby - 1) : 0;
    ofs[2] = (vltx && vrby) ? ((iltx - 1) << 7) + (irby - 1) : 0;
    ofs[3] = (vrbx && vlty) ? ((irbx - 1) << 7) + (ilty - 1) : 0;

    float pos[32];
    #pragma unroll
    for (int j = 0; j < 32; j++) pos[j] = 0.f;
    #pragma unroll
    for (int corner = 0; corner < 4; corner++) {
      const ushort* p = xb + ((size_t)ofs[corner] << 6) + c0;
      float wgt = wl[corner];
      ushort tmp[32];
      #pragma unroll
      for (int q = 0; q < 4; q++)
        *(uint4*)(tmp + q * 8) = *(const uint4*)(p + q * 8);
      #pragma unroll
      for (int j = 0; j < 32; j++) pos[j] += wgt * bf2f(tmp[j]);
    }
    // col: contiguous 32 bf16 at [pix][k*64 + c0]
    ushort ct[32];
    #pragma unroll
    for (int q = 0; q < 4; q++)
      *(uint4*)(ct + q * 8) = *(const uint4*)(colp + (k << 6) + c0 + q * 8);
    ushort vals[32];
    #pragma unroll
    for (int j = 0; j < 32; j++)
      vals[j] = f2bf((bf2f(ct[j]) + pos[j]) * mk);
    // write to LDS buffer k&1 with 8-slot rotation by pixel row
    ushort* su = &sU[k & 1][pxl << 6];
    #pragma unroll
    for (int q = 0; q < 4; q++) {
      int slot = ((chalf << 2) + q + pxl) & 7;
      *(uint4*)(su + slot * 8) = *(uint4*)(vals + q * 8);
    }
    __syncthreads();

    // ---- MFMA: 2 ks-steps over this k-tile ----
    const ushort* base = &sU[k & 1][0];
    #pragma unroll
    for (int khalf = 0; khalf < 2; khalf++) {
      int ks = (k << 1) + khalf;
      s16x8 af[2], bfr[4];
      #pragma unroll
      for (int mi = 0; mi < 2; mi++)
        af[mi] = *(const s16x8*)(W2pk + ((((ks << 2) + (ocq << 1) + mi) << 6) + lane) * 8);
      const int g0 = (khalf << 2) + kb;
      #pragma unroll
      for (int ni = 0; ni < 4; ni++) {
        int r = (pxq << 6) + ni * 16 + nif;
        int slot = (g0 + r) & 7;
        bfr[ni] = *(const s16x8*)(base + (r << 6) + slot * 8);
      }
      #pragma unroll
      for (int mi = 0; mi < 2; mi++)
        #pragma unroll
        for (int ni = 0; ni < 4; ni++)
          acc[mi][ni] = __builtin_amdgcn_mfma_f32_16x16x32_bf16(af[mi], bfr[ni], acc[mi][ni], 0, 0, 0);
    }
  }

  const int quad = lane >> 4;
  #pragma unroll
  for (int mi = 0; mi < 2; mi++) {
    #pragma unroll
    for (int ni = 0; ni < 4; ni++) {
      int hwp = hw0 + (pxq << 6) + ni * 16 + nif;
      #pragma unroll
      for (int r = 0; r < 4; r++) {
        int o = (ocq << 5) + mi * 16 + quad * 4 + r;
        out[(((size_t)b * 64 + o) << 14) + hwp] = acc[mi][ni][r];
      }
    }
  }
}

extern "C" void kernel_launch(void* const* d_in, const int* in_sizes, int n_in,
                              void* d_out, int out_size, void* d_ws, size_t ws_size,
                              hipStream_t stream) {
  const float* x     = (const float*)d_in[0];
  const float* ref   = (const float*)d_in[1];
  const float* wcd   = (const float*)d_in[2];
  const float* bcd   = (const float*)d_in[3];
  const float* wp    = (const float*)d_in[4];
  const float* bp    = (const float*)d_in[5];
  const float* wm    = (const float*)d_in[6];
  const float* bm    = (const float*)d_in[7];
  const float* wc    = (const float*)d_in[8];
  const float* bc    = (const float*)d_in[9];
  const float* wconv = (const float*)d_in[10];
  float* out = (float*)d_out;

  char* w8 = (char*)d_ws;
  ushort* Wpk     = (ushort*)(w8 + 0);           //    737,280 B
  float*  Bc      = (float*)(w8 + 737280);       //      2,560 B
  ushort* W2pk    = (ushort*)(w8 + 739840);      //     73,728 B
  ushort* fusedt  = (ushort*)(w8 + 813568);      //  8,388,608 B (pixel-major)
  float*  headom  = (float*)(w8 + 9202176);      //  7,077,888 B
  ushort* headcol = (ushort*)(w8 + 16280064);    // 75,497,472 B (pixel-major [pix][576])
  ushort* xtb     = (ushort*)(w8 + 91777536);    //  8,388,608 B -> total 100,166,144 B

  k_merge  <<<1440, 256, 0, stream>>>(wp, bp, wm, bm, wc, bc, wconv, Wpk, Bc, W2pk);
  k_fused  <<<256, 256, 0, stream>>>(x, ref, wcd, bcd, fusedt);
  k_xt     <<<1024, 256, 0, stream>>>(x, xtb);
  k_gemm   <<<512, 256, 0, stream>>>(Wpk, fusedt, Bc, headom, headcol);
  k_sampout<<<512, 256, 0, stream>>>(xtb, headom, headcol, W2pk, out);
}

// Round 11
// 242.519 us; speedup vs baseline: 1.8715x; 1.1528x over previous
//
#include <hip/hip_runtime.h>
#include <math.h>

typedef short s16x8 __attribute__((ext_vector_type(8)));
typedef float f32x4 __attribute__((ext_vector_type(4)));

__device__ inline ushort f2bf(float f) {
  unsigned u = __float_as_uint(f);
  u = (u + 0x7FFF + ((u >> 16) & 1)) >> 16;
  return (ushort)u;
}
__device__ inline float bf2f(ushort u) {
  return __uint_as_float(((unsigned)u) << 16);
}
// fast activations: v_exp_f32 + v_rcp_f32; saturate correctly at +/-inf.
__device__ inline float fast_tanh(float v) {
  float e = __builtin_amdgcn_exp2f(v * 2.8853900817779268f);   // exp(2v)
  return 1.f - 2.f * __builtin_amdgcn_rcpf(e + 1.f);
}
__device__ inline float fast_sigmoid(float v) {
  float e = __builtin_amdgcn_exp2f(v * -1.4426950408889634f);  // exp(-v)
  return __builtin_amdgcn_rcpf(1.f + e);
}

// ---- PERMUTED head-row space (640 rows):
//   g in [0,18): off | [18,27): mod | [27,64): pad | [64,640): col j=g-64=k*64+c
//     source col channel cc = c*9+k.
// ---- K0: pack weights into MFMA-fragment order in permuted row space ------------------
// Wpk[og 5][ks 18][ocq 2][mi 4][lane 64][e 8]; W2pk[ks 18][mi 4][lane 64][e 8].
__global__ __launch_bounds__(256) void k_merge(
    const float* __restrict__ wp, const float* __restrict__ bp,
    const float* __restrict__ wm, const float* __restrict__ bm,
    const float* __restrict__ wc, const float* __restrict__ bc,
    const float* __restrict__ wconv,
    ushort* __restrict__ Wpk, float* __restrict__ Bc, ushort* __restrict__ W2pk) {
  int i = blockIdx.x * 256 + threadIdx.x;
  if (i < 368640) {
    int e = i & 7, lane = (i >> 3) & 63, mi = (i >> 9) & 3, ocq = (i >> 11) & 1;
    int hi = i >> 12;                 // 0..89
    int ks = hi % 18, og = hi / 18;
    int g = og * 128 + ocq * 64 + mi * 16 + (lane & 15);
    int ci = ((ks & 1) << 5) + ((lane >> 4) << 3) + e;
    int kk = ks >> 1;
    int col = ci * 9 + kk;
    float v = 0.f;
    if (g < 18)       v = wp[g * 576 + col];
    else if (g < 27)  v = wm[(g - 18) * 576 + col];
    else if (g >= 64) {
      int j = g - 64;
      int cc = (j & 63) * 9 + (j >> 6);
      v = wc[cc * 576 + col];
    }
    Wpk[i] = f2bf(v);
  }
  if (i < 36864) {
    int e = i & 7, lane = (i >> 3) & 63, mi = (i >> 9) & 3, ks = i >> 11;  // 0..17
    int o = mi * 16 + (lane & 15);
    int p = (ks << 5) + ((lane >> 4) << 3) + e;
    int kk2 = p >> 6, c = p & 63;
    W2pk[i] = f2bf(wconv[o * 576 + c * 9 + kk2]);
  }
  if (i < 640) {
    float bv = 0.f;
    if (i < 18)       bv = bp[i];
    else if (i < 27)  bv = bm[i - 18];
    else if (i >= 64) {
      int j = i - 64;
      bv = bc[(j & 63) * 9 + (j >> 6)];
    }
    Bc[i] = bv;
  }
}

// ---- K1: fused = 1x1 conv over concat(x, ref) -> PIXEL-MAJOR bf16 fusedt[pix][64] -----
__global__ __launch_bounds__(256) void k_fused(
    const float* __restrict__ x, const float* __restrict__ ref,
    const float* __restrict__ wcd, const float* __restrict__ bcd,
    ushort* __restrict__ fusedt) {
  __shared__ float sw[128 * 64];
  __shared__ float sb[64];
  for (int i = threadIdx.x; i < 128 * 64; i += 256) {
    int ci = i >> 6, o = i & 63;
    sw[i] = wcd[o * 128 + ci];
  }
  if (threadIdx.x < 64) sb[threadIdx.x] = bcd[threadIdx.x];
  __syncthreads();

  int pix = blockIdx.x * 256 + threadIdx.x;
  int b = pix >> 14, hw = pix & 16383;
  const float* xb = x   + ((size_t)b * 64 << 14) + hw;
  const float* rb = ref + ((size_t)b * 64 << 14) + hw;

  float4 acc[16];
  #pragma unroll
  for (int o4 = 0; o4 < 16; o4++)
    acc[o4] = make_float4(sb[4*o4], sb[4*o4+1], sb[4*o4+2], sb[4*o4+3]);

  for (int ci = 0; ci < 64; ci++) {
    float v = xb[(size_t)ci << 14];
    const float4* wr = (const float4*)&sw[ci * 64];
    #pragma unroll
    for (int o4 = 0; o4 < 16; o4++) {
      float4 w4 = wr[o4];
      acc[o4].x += w4.x * v; acc[o4].y += w4.y * v;
      acc[o4].z += w4.z * v; acc[o4].w += w4.w * v;
    }
  }
  for (int ci = 0; ci < 64; ci++) {
    float v = rb[(size_t)ci << 14];
    const float4* wr = (const float4*)&sw[(64 + ci) * 64];
    #pragma unroll
    for (int o4 = 0; o4 < 16; o4++) {
      float4 w4 = wr[o4];
      acc[o4].x += w4.x * v; acc[o4].y += w4.y * v;
      acc[o4].z += w4.z * v; acc[o4].w += w4.w * v;
    }
  }
  ushort vals[64];
  #pragma unroll
  for (int o4 = 0; o4 < 16; o4++) {
    vals[4*o4+0] = f2bf(acc[o4].x); vals[4*o4+1] = f2bf(acc[o4].y);
    vals[4*o4+2] = f2bf(acc[o4].z); vals[4*o4+3] = f2bf(acc[o4].w);
  }
  ushort* fb = fusedt + ((size_t)pix << 6);
  #pragma unroll
  for (int q = 0; q < 8; q++)
    *(uint4*)(fb + q * 8) = *(uint4*)(vals + q * 8);
}

// ---- K2: xtb[b][hw][c] bf16 pixel-major transpose of x -------------------------------
__global__ __launch_bounds__(256) void k_xt(
    const float* __restrict__ x, ushort* __restrict__ xtb) {
  __shared__ float sx[64][65];
  const int t = threadIdx.x;
  const int b = blockIdx.x >> 8, hw0 = (blockIdx.x & 255) << 6;
  for (int i = t; i < 4096; i += 256) {
    int c = i >> 6, hwi = i & 63;
    sx[c][hwi] = x[((size_t)(b * 64 + c) << 14) + hw0 + hwi];
  }
  __syncthreads();
  for (int i = t; i < 4096; i += 256) {
    int hwi = i >> 6, c = i & 63;
    xtb[(((size_t)b << 14) + hw0 + hwi) * 64 + c] = f2bf(sx[c][hwi]);
  }
}

// ---- K3: FULLY FUSED head-GEMM + sampler + final GEMM ---------------------------------
// grid 512 (one 128-px image row per block); block 256 = 4 waves.
// Wave roles: pxq = wv&1 (64 px), rowq = wv>>1 (32 GEMM rows / 32 out-oc).
// Per k: col-GEMM (18 ks) -> tanh -> colT (LDS) -> sampler in-place -> MFMA vs W2pk.
// off/mod live only in homT (LDS). headcol/headom never touch HBM.
__global__ __launch_bounds__(256) void k_all(
    const ushort* __restrict__ Wpk, const ushort* __restrict__ fusedt,
    const float* __restrict__ Bc, const ushort* __restrict__ xtb,
    const ushort* __restrict__ W2pk, float* __restrict__ out) {
  __shared__ __align__(16) ushort sF[3 * 130 * 64];   // 49,920 B
  __shared__ __align__(16) ushort colT[128 * 64];     // 16,384 B
  __shared__ float homT[128 * 29];                    // 14,848 B (29-stride: conflict-free)
  const int t = threadIdx.x;
  const int lane = t & 63, wv = t >> 6;
  const int rowid = blockIdx.x;           // b*128 + h
  const int b = rowid >> 7, h = rowid & 127;
  const int hw0 = (rowid << 7) & 16383;

  // stage fused rows h-1..h+1, w1 in [0,130) covering gw in [-1,128]
  for (int idx = t; idx < 3120; idx += 256) {
    int p = idx >> 3, j = idx & 7;
    int row = p / 130, w1 = p - row * 130;
    int gh = h + row - 1, gw = w1 - 1;
    uint4 v = make_uint4(0u, 0u, 0u, 0u);
    if (gh >= 0 && gh < 128 && (unsigned)gw < 128u)
      v = *(const uint4*)(fusedt + ((size_t)((b << 14) + (gh << 7) + gw) << 6) + j * 8);
    int slot = (j + w1) & 7;
    *(uint4*)(sF + (p << 6) + slot * 8) = v;
  }
  __syncthreads();

  const int pxq = wv & 1, rowq = wv >> 1;
  const int nif = lane & 15, kb = lane >> 4, quad = lane >> 4;

  // ---- off/mod GEMM: permuted rows 0..31 (only rowq==0 waves; rows 32..63 are pad) ----
  if (rowq == 0) {
    f32x4 acc[2][4];
    #pragma unroll
    for (int mi = 0; mi < 2; mi++)
      #pragma unroll
      for (int ni = 0; ni < 4; ni++) acc[mi][ni] = (f32x4){0.f, 0.f, 0.f, 0.f};
    #pragma unroll 2
    for (int ks = 0; ks < 18; ks++) {
      const int kk = ks >> 1, half = ks & 1;
      const int dr = kk / 3, dc = kk - dr * 3;
      const ushort* wp8 = Wpk + ((size_t)(ks << 12)) + (lane << 3);  // og=0, ocq=0
      s16x8 af[2], bfr[4];
      #pragma unroll
      for (int mi = 0; mi < 2; mi++)
        af[mi] = *(const s16x8*)(wp8 + (mi << 9));       // miW = mi (rows 0..31)
      const int gci = half * 4 + kb;
      #pragma unroll
      for (int ni = 0; ni < 4; ni++) {
        int r = (pxq << 6) + ni * 16 + nif;
        int w1 = r + dc;
        int slot = (gci + w1) & 7;
        bfr[ni] = *(const s16x8*)(sF + ((dr * 130 + w1) << 6) + slot * 8);
      }
      #pragma unroll
      for (int mi = 0; mi < 2; mi++)
        #pragma unroll
        for (int ni = 0; ni < 4; ni++)
          acc[mi][ni] = __builtin_amdgcn_mfma_f32_16x16x32_bf16(af[mi], bfr[ni], acc[mi][ni], 0, 0, 0);
    }
    #pragma unroll
    for (int mi = 0; mi < 2; mi++) {
      #pragma unroll
      for (int ni = 0; ni < 4; ni++) {
        int px = (pxq << 6) + ni * 16 + nif;
        #pragma unroll
        for (int r = 0; r < 4; r++) {
          int g = mi * 16 + (quad << 2) + r;
          float v = acc[mi][ni][r] + Bc[g];
          if (g < 18)       homT[px * 29 + g] = v;
          else if (g < 27)  homT[px * 29 + g] = fast_sigmoid(v);
        }
      }
    }
  }

  // sampler per-pixel identity
  const int chalf = t >> 7, pxl = t & 127, c0 = chalf << 5;
  const int hw = hw0 + pxl;
  const int ww = hw & 127;                 // column; row is h
  const ushort* xb = xtb + ((size_t)b << 20);

  f32x4 aco[2][4];
  #pragma unroll
  for (int mi = 0; mi < 2; mi++)
    #pragma unroll
    for (int ni = 0; ni < 4; ni++) aco[mi][ni] = (f32x4){0.f, 0.f, 0.f, 0.f};

  #pragma unroll 1
  for (int k = 0; k < 9; k++) {
    // ---- col GEMM for this k: permuted rows 64+k*64 .. 128+k*64 ----
    const int q = 1 + k, og = q >> 1, ocq = q & 1;
    f32x4 acc[2][4];
    #pragma unroll
    for (int mi = 0; mi < 2; mi++)
      #pragma unroll
      for (int ni = 0; ni < 4; ni++) acc[mi][ni] = (f32x4){0.f, 0.f, 0.f, 0.f};
    #pragma unroll 2
    for (int ks = 0; ks < 18; ks++) {
      const int kk = ks >> 1, half = ks & 1;
      const int dr = kk / 3, dc = kk - dr * 3;
      const ushort* wp8 = Wpk + ((size_t)((((og * 18 + ks) << 1) + ocq) << 11)) + (lane << 3);
      s16x8 af[2], bfr[4];
      #pragma unroll
      for (int mi = 0; mi < 2; mi++)
        af[mi] = *(const s16x8*)(wp8 + (((rowq << 1) + mi) << 9));
      const int gci = half * 4 + kb;
      #pragma unroll
      for (int ni = 0; ni < 4; ni++) {
        int r = (pxq << 6) + ni * 16 + nif;
        int w1 = r + dc;
        int slot = (gci + w1) & 7;
        bfr[ni] = *(const s16x8*)(sF + ((dr * 130 + w1) << 6) + slot * 8);
      }
      #pragma unroll
      for (int mi = 0; mi < 2; mi++)
        #pragma unroll
        for (int ni = 0; ni < 4; ni++)
          acc[mi][ni] = __builtin_amdgcn_mfma_f32_16x16x32_bf16(af[mi], bfr[ni], acc[mi][ni], 0, 0, 0);
    }
    __syncthreads();   // previous k's MFMA reads of colT complete (k=0: homT visible too)

    // epilogue: tanh -> colT (slot-rotated: chunk = c>>3, slot = (chunk+px)&7)
    #pragma unroll
    for (int mi = 0; mi < 2; mi++) {
      #pragma unroll
      for (int ni = 0; ni < 4; ni++) {
        int px = (pxq << 6) + ni * 16 + nif;
        int c = (rowq << 5) + mi * 16 + (quad << 2);
        float4 b4 = *(const float4*)(Bc + 64 + (k << 6) + c);
        ushort v4[4];
        v4[0] = f2bf(fast_tanh(acc[mi][ni][0] + b4.x));
        v4[1] = f2bf(fast_tanh(acc[mi][ni][1] + b4.y));
        v4[2] = f2bf(fast_tanh(acc[mi][ni][2] + b4.z));
        v4[3] = f2bf(fast_tanh(acc[mi][ni][3] + b4.w));
        int slot = ((c >> 3) + px) & 7;
        *(uint2*)(colT + (px << 6) + slot * 8 + (c & 7)) = *(uint2*)v4;
      }
    }
    __syncthreads();   // colT visible to sampler

    // ---- sampler: 32 channels of pixel pxl, in-place update of colT ----
    {
      float ox = homT[pxl * 29 + k];
      float oy = homT[pxl * 29 + 9 + k];
      float mk = homT[pxl * 29 + 18 + k];
      float px_ = (float)(h + k / 3) + ox;
      float py_ = (float)(ww + k % 3) + oy;
      float fx = floorf(px_), fy = floorf(py_);
      float qltx = fminf(fmaxf(fx, 0.f), 129.f);
      float qlty = fminf(fmaxf(fy, 0.f), 129.f);
      float qrbx = fminf(fmaxf(fx + 1.f, 0.f), 129.f);
      float qrby = fminf(fmaxf(fy + 1.f, 0.f), 129.f);
      float sx = fminf(fmaxf(px_, 0.f), 129.f);
      float sy = fminf(fmaxf(py_, 0.f), 129.f);
      float ax = 1.f + qltx - sx, bx = 1.f - qrbx + sx;
      float ay = 1.f + qlty - sy, by = 1.f - qrby + sy;
      int iltx = (int)qltx, ilty = (int)qlty, irbx = (int)qrbx, irby = (int)qrby;
      bool vltx = (iltx >= 1) && (iltx <= 128);
      bool vlty = (ilty >= 1) && (ilty <= 128);
      bool vrbx = (irbx >= 1) && (irbx <= 128);
      bool vrby = (irby >= 1) && (irby <= 128);
      float wl[4];
      int   ofs[4];
      wl[0] = (vltx && vlty) ? ax * ay : 0.f;
      wl[1] = (vrbx && vrby) ? bx * by : 0.f;
      wl[2] = (vltx && vrby) ? ax * by : 0.f;
      wl[3] = (vrbx && vlty) ? bx * ay : 0.f;
      ofs[0] = (vltx && vlty) ? ((iltx - 1) << 7) + (ilty - 1) : 0;
      ofs[1] = (vrbx && vrby) ? ((irbx - 1) << 7) + (irby - 1) : 0;
      ofs[2] = (vltx && vrby) ? ((iltx - 1) << 7) + (irby - 1) : 0;
      ofs[3] = (vrbx && vlty) ? ((irbx - 1) << 7) + (ilty - 1) : 0;

      float pos[32];
      #pragma unroll
      for (int j = 0; j < 32; j++) pos[j] = 0.f;
      #pragma unroll
      for (int corner = 0; corner < 4; corner++) {
        const ushort* p = xb + ((size_t)ofs[corner] << 6) + c0;
        float wgt = wl[corner];
        ushort tmp[32];
        #pragma unroll
        for (int q2 = 0; q2 < 4; q2++)
          *(uint4*)(tmp + q2 * 8) = *(const uint4*)(p + q2 * 8);
        #pragma unroll
        for (int j = 0; j < 32; j++) pos[j] += wgt * bf2f(tmp[j]);
      }
      // read own col slots, update, write back (thread-exclusive -> no barrier)
      #pragma unroll
      for (int q2 = 0; q2 < 4; q2++) {
        int chunk = (chalf << 2) + q2;
        int slot = (chunk + pxl) & 7;
        ushort* cp = colT + (pxl << 6) + slot * 8;
        ushort ct[8];
        *(uint4*)ct = *(const uint4*)cp;
        #pragma unroll
        for (int j = 0; j < 8; j++)
          ct[j] = f2bf((bf2f(ct[j]) + pos[q2 * 8 + j]) * mk);
        *(uint4*)cp = *(uint4*)ct;
      }
    }
    __syncthreads();   // updated colT visible to MFMA

    // ---- final-GEMM MFMA: 2 ks-steps over this k-tile ----
    #pragma unroll
    for (int khalf = 0; khalf < 2; khalf++) {
      int ks2 = (k << 1) + khalf;
      s16x8 af[2], bfr[4];
      #pragma unroll
      for (int mi = 0; mi < 2; mi++)
        af[mi] = *(const s16x8*)(W2pk + ((((ks2 << 2) + (rowq << 1) + mi) << 6) + lane) * 8);
      const int g0 = (khalf << 2) + kb;
      #pragma unroll
      for (int ni = 0; ni < 4; ni++) {
        int r = (pxq << 6) + ni * 16 + nif;
        int slot = (g0 + r) & 7;
        bfr[ni] = *(const s16x8*)(colT + (r << 6) + slot * 8);
      }
      #pragma unroll
      for (int mi = 0; mi < 2; mi++)
        #pragma unroll
        for (int ni = 0; ni < 4; ni++)
          aco[mi][ni] = __builtin_amdgcn_mfma_f32_16x16x32_bf16(af[mi], bfr[ni], aco[mi][ni], 0, 0, 0);
    }
  }

  // ---- store out ----
  #pragma unroll
  for (int mi = 0; mi < 2; mi++) {
    #pragma unroll
    for (int ni = 0; ni < 4; ni++) {
      int hwp = hw0 + (pxq << 6) + ni * 16 + nif;
      #pragma unroll
      for (int r = 0; r < 4; r++) {
        int o = (rowq << 5) + mi * 16 + (quad << 2) + r;
        out[(((size_t)b * 64 + o) << 14) + hwp] = aco[mi][ni][r];
      }
    }
  }
}

extern "C" void kernel_launch(void* const* d_in, const int* in_sizes, int n_in,
                              void* d_out, int out_size, void* d_ws, size_t ws_size,
                              hipStream_t stream) {
  const float* x     = (const float*)d_in[0];
  const float* ref   = (const float*)d_in[1];
  const float* wcd   = (const float*)d_in[2];
  const float* bcd   = (const float*)d_in[3];
  const float* wp    = (const float*)d_in[4];
  const float* bp    = (const float*)d_in[5];
  const float* wm    = (const float*)d_in[6];
  const float* bm    = (const float*)d_in[7];
  const float* wc    = (const float*)d_in[8];
  const float* bc    = (const float*)d_in[9];
  const float* wconv = (const float*)d_in[10];
  float* out = (float*)d_out;

  char* w8 = (char*)d_ws;
  ushort* Wpk     = (ushort*)(w8 + 0);           //    737,280 B
  float*  Bc      = (float*)(w8 + 737280);       //      2,560 B
  ushort* W2pk    = (ushort*)(w8 + 739840);      //     73,728 B
  ushort* fusedt  = (ushort*)(w8 + 813568);      //  8,388,608 B (pixel-major)
  ushort* xtb     = (ushort*)(w8 + 9202176);     //  8,388,608 B -> total 17,590,784 B

  k_merge <<<1440, 256, 0, stream>>>(wp, bp, wm, bm, wc, bc, wconv, Wpk, Bc, W2pk);
  k_fused <<<256, 256, 0, stream>>>(x, ref, wcd, bcd, fusedt);
  k_xt    <<<1024, 256, 0, stream>>>(x, xtb);
  k_all   <<<512, 256, 0, stream>>>(Wpk, fusedt, Bc, xtb, W2pk, out);
}